// Round 8
// baseline (480.661 us; speedup 1.0000x reference)
//
#include <hip/hip_runtime.h>
#include <hip/hip_bf16.h>

#define NN   30000
#define DIN  128
#define NHD  256      // H*D
#define HH   4
#define DD   64
#define MM   64
#define KK   6
#define EE   480000
#define ZOFF 1920000  // 30000*64

__device__ __forceinline__ unsigned f2key(float f) {
    unsigned u = __float_as_uint(f);
    return (u & 0x80000000u) ? ~u : (u | 0x80000000u);
}
__device__ __forceinline__ float key2f(unsigned k) {
    return __uint_as_float((k & 0x80000000u) ? (k ^ 0x80000000u) : ~k);
}
__device__ __forceinline__ unsigned short f2bf(float f) {   // RNE
    unsigned u = __float_as_uint(f);
    unsigned r = ((u >> 16) & 1u) + 0x7fffu;
    return (unsigned short)((u + r) >> 16);
}

// ---------------------------------------------------------------- init
__global__ void init_kernel(unsigned* gmax) {
    if (threadIdx.x < HH) gmax[threadIdx.x] = 0u;
}

// ---------------------------------------------------------------- K1: qkv GEMM
__device__ __forceinline__ void gemm_one(const float* __restrict__ W,
                                         const float* __restrict__ b,
                                         float* __restrict__ O, float sc,
                                         const float (*zsh)[132], float* wsh,
                                         int t, int n0) {
    const int tx = t & 15, ty = t >> 4;
    float4 acc[4][4];
    #pragma unroll
    for (int i = 0; i < 4; ++i)
        #pragma unroll
        for (int g = 0; g < 4; ++g) acc[i][g] = make_float4(0.f, 0.f, 0.f, 0.f);
    const float4* W4 = (const float4*)W;
    for (int rt = 0; rt < 4; ++rt) {
        __syncthreads();
        #pragma unroll
        for (int q = 0; q < 8; ++q) {
            int idx4 = t + q * 256;            // 2048 float4 = 32 rows x 64
            *(float4*)&wsh[idx4 * 4] = W4[rt * 2048 + idx4];
        }
        __syncthreads();
        #pragma unroll 4
        for (int j = 0; j < 32; ++j) {
            const int col = rt * 32 + j;
            float a0 = zsh[ty][col];
            float a1 = zsh[ty + 16][col];
            float a2 = zsh[ty + 32][col];
            float a3 = zsh[ty + 48][col];
            #pragma unroll
            for (int g = 0; g < 4; ++g) {
                float4 bb = *(const float4*)&wsh[j * 256 + g * 64 + tx * 4];
                acc[0][g].x += a0 * bb.x; acc[0][g].y += a0 * bb.y;
                acc[0][g].z += a0 * bb.z; acc[0][g].w += a0 * bb.w;
                acc[1][g].x += a1 * bb.x; acc[1][g].y += a1 * bb.y;
                acc[1][g].z += a1 * bb.z; acc[1][g].w += a1 * bb.w;
                acc[2][g].x += a2 * bb.x; acc[2][g].y += a2 * bb.y;
                acc[2][g].z += a2 * bb.z; acc[2][g].w += a2 * bb.w;
                acc[3][g].x += a3 * bb.x; acc[3][g].y += a3 * bb.y;
                acc[3][g].z += a3 * bb.z; acc[3][g].w += a3 * bb.w;
            }
        }
    }
    #pragma unroll
    for (int g = 0; g < 4; ++g) {
        float4 bias = *(const float4*)&b[g * 64 + tx * 4];
        #pragma unroll
        for (int i = 0; i < 4; ++i) {
            int n = n0 + ty + i * 16;
            if (n < NN) {
                float4 o;
                o.x = (acc[i][g].x + bias.x) * sc;
                o.y = (acc[i][g].y + bias.y) * sc;
                o.z = (acc[i][g].z + bias.z) * sc;
                o.w = (acc[i][g].w + bias.w) * sc;
                *(float4*)&O[(size_t)n * NHD + g * 64 + tx * 4] = o;
            }
        }
    }
}

__global__ __launch_bounds__(256) void qkv_kernel(
    const float* __restrict__ z,
    const float* __restrict__ Wq, const float* __restrict__ bq,
    const float* __restrict__ Wk, const float* __restrict__ bk,
    const float* __restrict__ Wv, const float* __restrict__ bv,
    float* __restrict__ qb, float* __restrict__ kb, float* __restrict__ vb) {
    __shared__ __align__(16) float zsh[64][132];
    __shared__ __align__(16) float wsh[32 * 256];
    const int t = threadIdx.x;
    const int n0 = blockIdx.x * 64;
    const float4* z4 = (const float4*)z;
    #pragma unroll
    for (int q = 0; q < 8; ++q) {
        int idx4 = t + q * 256;                // 2048 float4 = 64 rows x 32
        int row = idx4 >> 5, c4 = idx4 & 31;
        float4 v = make_float4(0.f, 0.f, 0.f, 0.f);
        if (n0 + row < NN) v = z4[(size_t)(n0 + row) * 32 + c4];
        *(float4*)&zsh[row][c4 * 4] = v;
    }
    gemm_one(Wq, bq, qb, 2.0f, zsh, wsh, t, n0);
    gemm_one(Wk, bk, kb, 2.0f, zsh, wsh, t, n0);
    gemm_one(Wv, bv, vb, 1.0f, zsh, wsh, t, n0);
}

// ---------------------------------------------------------------- K2: random features (GEMM form)
__global__ __launch_bounds__(256) void feat_kernel(
    float* __restrict__ qb, float* __restrict__ kb,
    const float* __restrict__ proj, unsigned* __restrict__ gmax,
    unsigned short* __restrict__ qbh) {
    __shared__ __align__(16) float pT[64][68];   // pT[d][m]
    __shared__ __align__(16) float tT[64][68];   // tT[d][n]
    __shared__ float diag_sh[64];
    __shared__ float wmax_sh[4];
    const int t = threadIdx.x;
    const int h = blockIdx.y;
    const int n0 = blockIdx.x * 64;
    const int tx = t & 15, ty = t >> 4;
    const float dn = 0.35355339059327373f;  // 64^-0.25
    const float4* proj4 = (const float4*)proj;
    #pragma unroll
    for (int q = 0; q < 4; ++q) {
        int idx4 = t + q * 256;
        int m = idx4 >> 4, d4 = idx4 & 15;
        float4 v = proj4[m * 16 + d4];
        pT[d4 * 4 + 0][m] = v.x; pT[d4 * 4 + 1][m] = v.y;
        pT[d4 * 4 + 2][m] = v.z; pT[d4 * 4 + 3][m] = v.w;
    }
    #pragma unroll
    for (int pass = 0; pass < 2; ++pass) {
        float* buf = pass ? kb : qb;
        const float4* b4 = (const float4*)buf;
        __syncthreads();
        #pragma unroll
        for (int q = 0; q < 4; ++q) {
            int idx4 = t + q * 256;
            int n = idx4 >> 4, d4 = idx4 & 15;
            float4 v = make_float4(0.f, 0.f, 0.f, 0.f);
            if (n0 + n < NN) v = b4[(n0 + n) * 64 + h * 16 + d4];
            tT[d4 * 4 + 0][n] = v.x * dn; tT[d4 * 4 + 1][n] = v.y * dn;
            tT[d4 * 4 + 2][n] = v.z * dn; tT[d4 * 4 + 3][n] = v.w * dn;
        }
        __syncthreads();
        if (t < 64) {
            float s = 0.f;
            #pragma unroll 8
            for (int d = 0; d < 64; ++d) { float v = tT[d][t]; s += v * v; }
            diag_sh[t] = 0.5f * s;
        }
        __syncthreads();
        float acc[4][4];
        #pragma unroll
        for (int i = 0; i < 4; ++i)
            #pragma unroll
            for (int j = 0; j < 4; ++j) acc[i][j] = 0.f;
        #pragma unroll 8
        for (int d = 0; d < 64; ++d) {
            float4 a = *(const float4*)&tT[d][ty * 4];
            float4 b = *(const float4*)&pT[d][tx * 4];
            float a_[4] = {a.x, a.y, a.z, a.w};
            float b_[4] = {b.x, b.y, b.z, b.w};
            #pragma unroll
            for (int i = 0; i < 4; ++i)
                #pragma unroll
                for (int j = 0; j < 4; ++j) acc[i][j] += a_[i] * b_[j];
        }
        if (pass == 0) {
            #pragma unroll
            for (int i = 0; i < 4; ++i) {
                int n = n0 + ty * 4 + i;
                float mx = fmaxf(fmaxf(acc[i][0], acc[i][1]), fmaxf(acc[i][2], acc[i][3]));
                mx = fmaxf(mx, __shfl_xor(mx, 1, 64));
                mx = fmaxf(mx, __shfl_xor(mx, 2, 64));
                mx = fmaxf(mx, __shfl_xor(mx, 4, 64));
                mx = fmaxf(mx, __shfl_xor(mx, 8, 64));
                if (n < NN) {
                    float dg = diag_sh[ty * 4 + i] + mx;
                    float4 o;
                    o.x = 0.125f * (__expf(acc[i][0] - dg) + 1e-6f);
                    o.y = 0.125f * (__expf(acc[i][1] - dg) + 1e-6f);
                    o.z = 0.125f * (__expf(acc[i][2] - dg) + 1e-6f);
                    o.w = 0.125f * (__expf(acc[i][3] - dg) + 1e-6f);
                    *(float4*)&qb[n * NHD + h * DD + tx * 4] = o;
                    if (qbh) {
                        ushort4 u;
                        u.x = f2bf(o.x); u.y = f2bf(o.y);
                        u.z = f2bf(o.z); u.w = f2bf(o.w);
                        *(ushort4*)&qbh[n * NHD + h * DD + tx * 4] = u;
                    }
                }
            }
        } else {
            float km = -3.4e38f;
            #pragma unroll
            for (int i = 0; i < 4; ++i) {
                int n = n0 + ty * 4 + i;
                if (n < NN) {
                    float dg = diag_sh[ty * 4 + i];
                    float4 o;
                    o.x = acc[i][0] - dg; o.y = acc[i][1] - dg;
                    o.z = acc[i][2] - dg; o.w = acc[i][3] - dg;
                    *(float4*)&kb[n * NHD + h * DD + tx * 4] = o;
                    km = fmaxf(km, fmaxf(fmaxf(acc[i][0], acc[i][1]),
                                         fmaxf(acc[i][2], acc[i][3])));
                }
            }
            #pragma unroll
            for (int off = 1; off < 64; off <<= 1) km = fmaxf(km, __shfl_xor(km, off, 64));
            if ((t & 63) == 0) wmax_sh[t >> 6] = km;
            __syncthreads();
            if (t == 0) {
                float m2 = fmaxf(fmaxf(wmax_sh[0], wmax_sh[1]), fmaxf(wmax_sh[2], wmax_sh[3]));
                atomicMax(&gmax[h], f2key(m2));
            }
        }
    }
}

// ---------------------------------------------------------------- K3: kp finalize (float4 + bf16 mirror)
__global__ void kfin_kernel(float* __restrict__ kb, const unsigned* __restrict__ gmax,
                            unsigned short* __restrict__ kbh) {
    int idx = (blockIdx.x * 256 + threadIdx.x) * 4;   // 7,680,000 total elems
    int h = (idx >> 6) & 3;
    float mx = key2f(gmax[h]);
    float4 v = *(float4*)&kb[idx];
    v.x = 0.125f * (__expf(v.x - mx) + 1e-6f);
    v.y = 0.125f * (__expf(v.y - mx) + 1e-6f);
    v.z = 0.125f * (__expf(v.z - mx) + 1e-6f);
    v.w = 0.125f * (__expf(v.w - mx) + 1e-6f);
    *(float4*)&kb[idx] = v;
    if (kbh) {
        ushort4 u;
        u.x = f2bf(v.x); u.y = f2bf(v.y); u.z = f2bf(v.z); u.w = f2bf(v.w);
        *(ushort4*)&kbh[idx] = u;
    }
}

// ---------------------------------------------------------------- K4: kvs partials (all 6 k fused)
// grid (ncs, HH): each block reads its kb/vb chunk ONCE, computes all 6 samples.
__global__ __launch_bounds__(256) void kvs_kernel(
    const float* __restrict__ kb, const float* __restrict__ vb,
    const float* __restrict__ gum,
    float* __restrict__ kvsp, float* __restrict__ ksp, float* __restrict__ ksump,
    int chunk) {
    __shared__ __align__(16) float k_sh[32 * 64];
    __shared__ __align__(16) float v_sh[32 * 64];
    __shared__ float w_sh[KK][480];
    const int c = blockIdx.x, h = blockIdx.y;
    const int t = threadIdx.x;
    const int lane = t & 63;   // m
    const int wv = t >> 6;     // d-block
    const int n0 = c * chunk;
    const int n1 = (n0 + chunk < NN) ? (n0 + chunk) : NN;
    const int lenp = (chunk + 31) & ~31;
    for (int i = t; i < lenp; i += 256) {
        int n = n0 + i;
        bool ok = (n < n1);
        #pragma unroll
        for (int k = 0; k < KK; ++k)
            w_sh[k][i] = ok ? __expf(gum[n * 24 + h * KK + k] * 4.0f) : 0.f;
    }
    float acc[KK][16];
    #pragma unroll
    for (int k = 0; k < KK; ++k)
        #pragma unroll
        for (int i = 0; i < 16; ++i) acc[k][i] = 0.f;
    float ks_acc[KK] = {0.f, 0.f, 0.f, 0.f, 0.f, 0.f};
    float ksum_acc = 0.f;
    const float4* kb4 = (const float4*)kb;
    const float4* vb4 = (const float4*)vb;
    for (int nt = n0; nt < n1; nt += 32) {
        __syncthreads();
        #pragma unroll
        for (int q = 0; q < 4; ++q) {
            int idx4 = t + q * 256;       // 1024 float4 = 32 rows x 32
            int row = idx4 >> 5;
            int wi = idx4 & 31;
            int n = nt + row;
            float4 val = make_float4(0.f, 0.f, 0.f, 0.f);
            if (n < n1)
                val = (wi < 16) ? kb4[n * 64 + h * 16 + wi]
                                : vb4[n * 64 + h * 16 + (wi - 16)];
            if (wi < 16) *(float4*)&k_sh[row * 64 + wi * 4] = val;
            else         *(float4*)&v_sh[row * 64 + (wi - 16) * 4] = val;
        }
        __syncthreads();
        const int bw = nt - n0;
        const int jmax = (n1 - nt < 32) ? (n1 - nt) : 32;
        #pragma unroll 2
        for (int j = 0; j < jmax; ++j) {
            float kpm = k_sh[j * 64 + lane];
            ksum_acc += kpm;
            const float4* v4 = (const float4*)&v_sh[j * 64 + wv * 16];
            float4 vv0 = v4[0], vv1 = v4[1], vv2 = v4[2], vv3 = v4[3];
            #pragma unroll
            for (int k = 0; k < KK; ++k) {
                float a = kpm * w_sh[k][bw + j];
                ks_acc[k] += a;
                acc[k][ 0] += a * vv0.x; acc[k][ 1] += a * vv0.y;
                acc[k][ 2] += a * vv0.z; acc[k][ 3] += a * vv0.w;
                acc[k][ 4] += a * vv1.x; acc[k][ 5] += a * vv1.y;
                acc[k][ 6] += a * vv1.z; acc[k][ 7] += a * vv1.w;
                acc[k][ 8] += a * vv2.x; acc[k][ 9] += a * vv2.y;
                acc[k][10] += a * vv2.z; acc[k][11] += a * vv2.w;
                acc[k][12] += a * vv3.x; acc[k][13] += a * vv3.y;
                acc[k][14] += a * vv3.z; acc[k][15] += a * vv3.w;
            }
        }
    }
    #pragma unroll
    for (int k = 0; k < KK; ++k) {
        int base = (((c * HH + h) * KK + k) * 64 + lane) * 64 + wv * 16;
        float4* o4 = (float4*)&kvsp[base];
        o4[0] = make_float4(acc[k][0], acc[k][1], acc[k][2], acc[k][3]);
        o4[1] = make_float4(acc[k][4], acc[k][5], acc[k][6], acc[k][7]);
        o4[2] = make_float4(acc[k][8], acc[k][9], acc[k][10], acc[k][11]);
        o4[3] = make_float4(acc[k][12], acc[k][13], acc[k][14], acc[k][15]);
    }
    if (wv == 0) {
        #pragma unroll
        for (int k = 0; k < KK; ++k)
            ksp[((c * HH + h) * KK + k) * 64 + lane] = ks_acc[k];
        ksump[(c * HH + h) * 64 + lane] = ksum_acc;
    }
}

// ---------------------------------------------------------------- K5: reduce partials
__global__ void reduce_kernel(const float* __restrict__ kvsp, const float* __restrict__ ksp,
                              const float* __restrict__ ksump,
                              float* __restrict__ kvs, float* __restrict__ kss,
                              float* __restrict__ ksum, int ncs) {
    int idx = blockIdx.x * 256 + threadIdx.x;
    if (idx < 98304) {
        float s = 0.f;
        for (int c = 0; c < ncs; ++c) s += kvsp[c * 98304 + idx];
        kvs[idx] = s;
    } else if (idx < 98304 + 1536) {
        int o = idx - 98304;
        float s = 0.f;
        for (int c = 0; c < ncs; ++c) s += ksp[c * 1536 + o];
        kss[o] = s;
    } else if (idx < 98304 + 1536 + 256) {
        int o = idx - 98304 - 1536;
        float s = 0.f;
        for (int c = 0; c < ncs; ++c) s += ksump[c * 256 + o];
        ksum[o] = s;
    }
}

// ---------------------------------------------------------------- K6: z_num/z_den -> z_out, norm
__global__ __launch_bounds__(256) void znum_kernel(
    const float* __restrict__ qb, const float* __restrict__ kvs,
    const float* __restrict__ kss, const float* __restrict__ ksum,
    float* __restrict__ zout, float* __restrict__ nrm) {
    __shared__ __align__(16) float smem[13312];
    float* kvs_sh  = smem;          // 4096 (phase 2)
    float* ks_sh   = smem;          // 384  (phase 1 only)
    float* ksum_sh = smem + 384;    // 64   (phase 1 only)
    float* qpT     = smem + 4096;   // 8448
    float* zdi     = smem + 12544;  // 768
    const int t = threadIdx.x;
    const int tile = blockIdx.x, h = blockIdx.y;
    const int n0 = tile * 128;
    for (int i = t; i < 384; i += 256) ks_sh[i] = kss[h * 384 + i];
    if (t < 64) ksum_sh[t] = ksum[h * 64 + t];
    #pragma unroll
    for (int q = 0; q < 32; ++q) {
        int idx = t + q * 256;
        int nn2 = idx >> 6, m = idx & 63;
        int n = n0 + nn2;
        qpT[m * 132 + nn2] = (n < NN) ? qb[n * NHD + h * DD + m] : 0.f;
    }
    __syncthreads();
    #pragma unroll
    for (int p = 0; p < 4; ++p) {
        int idx = t + p * 256;
        if (idx < 768) {
            int node = idx / 6, k = idx % 6;
            float s = 0.f;
            for (int m = 0; m < 64; ++m) s += qpT[m * 132 + node] * ks_sh[k * 64 + m];
            zdi[idx] = 1.0f / s;
        } else if (idx < 896) {
            int node = idx - 768;
            float s = 0.f;
            for (int m = 0; m < 64; ++m) s += qpT[m * 132 + node] * ksum_sh[m];
            int n = n0 + node;
            if (n < NN) nrm[n * HH + h] = s;
        }
    }
    __syncthreads();
    const int tc = t & 15, tr = t >> 4;
    float out[8][4];
    #pragma unroll
    for (int i = 0; i < 8; ++i) { out[i][0] = 0.f; out[i][1] = 0.f; out[i][2] = 0.f; out[i][3] = 0.f; }
    for (int k = 0; k < KK; ++k) {
        const float* src = kvs + h * 24576 + k * 4096;
        #pragma unroll
        for (int q = 0; q < 16; ++q) kvs_sh[t + q * 256] = src[t + q * 256];
        __syncthreads();
        float s[8][4];
        #pragma unroll
        for (int i = 0; i < 8; ++i) { s[i][0] = 0.f; s[i][1] = 0.f; s[i][2] = 0.f; s[i][3] = 0.f; }
        const float* kbase = kvs_sh + tc * 4;
        #pragma unroll 4
        for (int m = 0; m < 64; ++m) {
            float4 b = *(const float4*)(kbase + m * 64);
            float a[8];
            *(float4*)&a[0] = *(const float4*)&qpT[m * 132 + tr * 8];
            *(float4*)&a[4] = *(const float4*)&qpT[m * 132 + tr * 8 + 4];
            #pragma unroll
            for (int i = 0; i < 8; ++i) {
                s[i][0] += a[i] * b.x;
                s[i][1] += a[i] * b.y;
                s[i][2] += a[i] * b.z;
                s[i][3] += a[i] * b.w;
            }
        }
        #pragma unroll
        for (int i = 0; i < 8; ++i) {
            float zv = zdi[(tr * 8 + i) * 6 + k];
            out[i][0] += s[i][0] * zv;
            out[i][1] += s[i][1] * zv;
            out[i][2] += s[i][2] * zv;
            out[i][3] += s[i][3] * zv;
        }
        __syncthreads();
    }
    const float inv6 = 1.0f / 6.0f;
    #pragma unroll
    for (int i = 0; i < 8; ++i) {
        int n = n0 + tr * 8 + i;
        if (n < NN) {
            float4 o = make_float4(out[i][0] * inv6, out[i][1] * inv6,
                                   out[i][2] * inv6, out[i][3] * inv6);
            *(float4*)&zout[n * NHD + h * DD + tc * 4] = o;
        }
    }
}

// ---------------------------------------------------------------- K7: output projection (f32 out)
__global__ __launch_bounds__(256) void outproj_kernel(
    const float* __restrict__ zout, const float* __restrict__ Wo,
    const float* __restrict__ bo, float* __restrict__ out) {
    __shared__ float zsh[16][NHD];
    const int t = threadIdx.x;
    const int n0 = blockIdx.x * 16;
    #pragma unroll
    for (int q = 0; q < 16; ++q) {
        int idx = t + q * 256;
        int nn2 = idx >> 8, r = idx & 255;
        zsh[nn2][r] = zout[(n0 + nn2) * NHD + r];
    }
    __syncthreads();
    const int c = t & 63, g = t >> 6;
    float acc[4];
    #pragma unroll
    for (int i = 0; i < 4; ++i) acc[i] = bo[c];
    for (int r = 0; r < 256; ++r) {
        float w = Wo[r * 64 + c];
        #pragma unroll
        for (int i = 0; i < 4; ++i) acc[i] += zsh[g + 4 * i][r] * w;
    }
    #pragma unroll
    for (int i = 0; i < 4; ++i)
        out[(n0 + g + 4 * i) * 64 + c] = acc[i];
}

// ---------------------------------------------------------------- K8a: edges, bf16 gather (8 edges/block)
__global__ __launch_bounds__(256) void edge_bf16_kernel(
    const unsigned short* __restrict__ qbh, const unsigned short* __restrict__ kbh,
    const int* __restrict__ ei, const float* __restrict__ nrm,
    float* __restrict__ out) {
    const int t = threadIdx.x;
    const int lane5 = t & 31;
    const int e = blockIdx.x * 8 + (t >> 5);
    const int s = ei[e], d = ei[EE + e];
    const uint4* q4 = (const uint4*)qbh;
    const uint4* k4 = (const uint4*)kbh;
    uint4 qv = q4[d * 32 + lane5];
    uint4 kv = k4[s * 32 + lane5];
    const unsigned short* qs = (const unsigned short*)&qv;
    const unsigned short* ks = (const unsigned short*)&kv;
    float p = 0.f;
    #pragma unroll
    for (int i = 0; i < 8; ++i) {
        float qf = __uint_as_float((unsigned)qs[i] << 16);
        float kf = __uint_as_float((unsigned)ks[i] << 16);
        p += qf * kf;
    }
    p += __shfl_xor(p, 1, 64);
    p += __shfl_xor(p, 2, 64);
    p += __shfl_xor(p, 4, 64);
    if ((lane5 & 7) == 0) {
        int h = lane5 >> 3;
        out[ZOFF + e * 4 + h] = p / nrm[d * HH + h];
    }
}

// ---------------------------------------------------------------- K8b: edges, f32 fallback
__global__ __launch_bounds__(256) void edge_kernel(
    const float* __restrict__ qb, const float* __restrict__ kb,
    const int* __restrict__ ei, const float* __restrict__ nrm,
    float* __restrict__ out) {
    const int t = threadIdx.x;
    const int lane = t & 63, w = t >> 6;
    const int e = blockIdx.x * 4 + w;
    const int s = ei[e], d = ei[EE + e];
    float4 qv = *(const float4*)&qb[d * NHD + lane * 4];
    float4 kv = *(const float4*)&kb[s * NHD + lane * 4];
    float p = qv.x * kv.x + qv.y * kv.y + qv.z * kv.z + qv.w * kv.w;
    #pragma unroll
    for (int off = 1; off < 16; off <<= 1) p += __shfl_xor(p, off, 64);
    if ((lane & 15) == 0) {
        int h = lane >> 4;
        out[ZOFF + e * 4 + h] = p / nrm[d * HH + h];
    }
}

// ---------------------------------------------------------------- launch
extern "C" void kernel_launch(void* const* d_in, const int* in_sizes, int n_in,
                              void* d_out, int out_size, void* d_ws, size_t ws_size,
                              hipStream_t stream) {
    (void)in_sizes; (void)n_in; (void)out_size;
    const float* z  = (const float*)d_in[0];
    const float* Wq = (const float*)d_in[1];
    const float* bq = (const float*)d_in[2];
    const float* Wk = (const float*)d_in[3];
    const float* bk = (const float*)d_in[4];
    const float* Wv = (const float*)d_in[5];
    const float* bv = (const float*)d_in[6];
    const float* Wo = (const float*)d_in[7];
    const float* bo = (const float*)d_in[8];
    const float* proj = (const float*)d_in[9];
    const float* gum  = (const float*)d_in[10];
    const int*   ei   = (const int*)d_in[11];
    float* out = (float*)d_out;
    float* ws = (float*)d_ws;

    // Ladder (float units): base=23,260,100; +bf16 mirrors 7,680,000; +ncs*100,096.
    // chunk must stay <= 480 (w_sh width), so ncs >= 64.
    const size_t fs = ws_size / 4;
    bool use_bf16; int ncs;
    if      (fs >= 43752388) { use_bf16 = true;  ncs = 128; }
    else if (fs >= 37346244) { use_bf16 = true;  ncs = 64;  }
    else if (fs >= 36072388) { use_bf16 = false; ncs = 128; }
    else if (fs >= 29666244) { use_bf16 = false; ncs = 64;  }
    else return;
    const int chunk = (NN + ncs - 1) / ncs;   // 235 or 469

    float* qb    = ws;                  // 7,680,000
    float* kb    = ws + 7680000;        // 7,680,000
    float* vb    = ws + 15360000;       // 7,680,000 (reused as zout after kvs)
    float* zout  = vb;
    float* kvs   = ws + 23040000;       // 98,304
    float* kss   = ws + 23138304;       // 1,536
    float* ksum  = ws + 23139840;       // 256
    float* nrm   = ws + 23140096;       // 120,000
    unsigned* gmax = (unsigned*)(ws + 23260096);  // 4
    float* p = ws + 23260100;
    unsigned short* qbh = nullptr;
    unsigned short* kbh = nullptr;
    if (use_bf16) {
        qbh = (unsigned short*)p;              // 7,680,000 bf16 = 3,840,000 fl
        kbh = (unsigned short*)(p + 3840000);  // 7,680,000 bf16
        p += 7680000;
    }
    float* ksp   = p;                           // ncs*1536
    float* ksump = ksp + (size_t)ncs * 1536;    // ncs*256
    float* kvsp  = ksump + (size_t)ncs * 256;   // ncs*98304

    init_kernel<<<1, 64, 0, stream>>>(gmax);
    qkv_kernel<<<469, 256, 0, stream>>>(z, Wq, bq, Wk, bk, Wv, bv, qb, kb, vb);
    feat_kernel<<<dim3(469, HH), 256, 0, stream>>>(qb, kb, proj, gmax, qbh);
    kfin_kernel<<<7500, 256, 0, stream>>>(kb, gmax, kbh);
    kvs_kernel<<<dim3(ncs, HH), 256, 0, stream>>>(kb, vb, gum, kvsp, ksp, ksump, chunk);
    reduce_kernel<<<392, 256, 0, stream>>>(kvsp, ksp, ksump, kvs, kss, ksum, ncs);
    znum_kernel<<<dim3(235, HH), 256, 0, stream>>>(qb, kvs, kss, ksum, zout, nrm);
    outproj_kernel<<<1875, 256, 0, stream>>>(zout, Wo, bo, out);
    if (use_bf16) {
        edge_bf16_kernel<<<60000, 256, 0, stream>>>(qbh, kbh, ei, nrm, out);
    } else {
        edge_kernel<<<120000, 256, 0, stream>>>(qb, kb, ei, nrm, out);
    }
}

// Round 10
// 418.794 us; speedup vs baseline: 1.1477x; 1.1477x over previous
//
#include <hip/hip_runtime.h>
#include <hip/hip_bf16.h>

#define NN   30000
#define DIN  128
#define NHD  256      // H*D
#define HH   4
#define DD   64
#define MM   64
#define KK   6
#define EE   480000
#define ZOFF 1920000  // 30000*64

typedef __attribute__((ext_vector_type(8))) short bf16x8;
typedef __attribute__((ext_vector_type(4))) float f32x4;

__device__ __forceinline__ unsigned f2key(float f) {
    unsigned u = __float_as_uint(f);
    return (u & 0x80000000u) ? ~u : (u | 0x80000000u);
}
__device__ __forceinline__ float key2f(unsigned k) {
    return __uint_as_float((k & 0x80000000u) ? (k ^ 0x80000000u) : ~k);
}
__device__ __forceinline__ unsigned short f2bf(float f) {   // RNE
    unsigned u = __float_as_uint(f);
    unsigned r = ((u >> 16) & 1u) + 0x7fffu;
    return (unsigned short)((u + r) >> 16);
}

// ---------------------------------------------------------------- init
__global__ void init_kernel(unsigned* gmax) {
    if (threadIdx.x < HH) gmax[threadIdx.x] = 0u;
}

// ---------------------------------------------------------------- K1: qkv GEMM
__device__ __forceinline__ void gemm_one(const float* __restrict__ W,
                                         const float* __restrict__ b,
                                         float* __restrict__ O, float sc,
                                         const float (*zsh)[132], float* wsh,
                                         int t, int n0) {
    const int tx = t & 15, ty = t >> 4;
    float4 acc[4][4];
    #pragma unroll
    for (int i = 0; i < 4; ++i)
        #pragma unroll
        for (int g = 0; g < 4; ++g) acc[i][g] = make_float4(0.f, 0.f, 0.f, 0.f);
    const float4* W4 = (const float4*)W;
    for (int rt = 0; rt < 4; ++rt) {
        __syncthreads();
        #pragma unroll
        for (int q = 0; q < 8; ++q) {
            int idx4 = t + q * 256;            // 2048 float4 = 32 rows x 64
            *(float4*)&wsh[idx4 * 4] = W4[rt * 2048 + idx4];
        }
        __syncthreads();
        #pragma unroll 4
        for (int j = 0; j < 32; ++j) {
            const int col = rt * 32 + j;
            float a0 = zsh[ty][col];
            float a1 = zsh[ty + 16][col];
            float a2 = zsh[ty + 32][col];
            float a3 = zsh[ty + 48][col];
            #pragma unroll
            for (int g = 0; g < 4; ++g) {
                float4 bb = *(const float4*)&wsh[j * 256 + g * 64 + tx * 4];
                acc[0][g].x += a0 * bb.x; acc[0][g].y += a0 * bb.y;
                acc[0][g].z += a0 * bb.z; acc[0][g].w += a0 * bb.w;
                acc[1][g].x += a1 * bb.x; acc[1][g].y += a1 * bb.y;
                acc[1][g].z += a1 * bb.z; acc[1][g].w += a1 * bb.w;
                acc[2][g].x += a2 * bb.x; acc[2][g].y += a2 * bb.y;
                acc[2][g].z += a2 * bb.z; acc[2][g].w += a2 * bb.w;
                acc[3][g].x += a3 * bb.x; acc[3][g].y += a3 * bb.y;
                acc[3][g].z += a3 * bb.z; acc[3][g].w += a3 * bb.w;
            }
        }
    }
    #pragma unroll
    for (int g = 0; g < 4; ++g) {
        float4 bias = *(const float4*)&b[g * 64 + tx * 4];
        #pragma unroll
        for (int i = 0; i < 4; ++i) {
            int n = n0 + ty + i * 16;
            if (n < NN) {
                float4 o;
                o.x = (acc[i][g].x + bias.x) * sc;
                o.y = (acc[i][g].y + bias.y) * sc;
                o.z = (acc[i][g].z + bias.z) * sc;
                o.w = (acc[i][g].w + bias.w) * sc;
                *(float4*)&O[(size_t)n * NHD + g * 64 + tx * 4] = o;
            }
        }
    }
}

__global__ __launch_bounds__(256) void qkv_kernel(
    const float* __restrict__ z,
    const float* __restrict__ Wq, const float* __restrict__ bq,
    const float* __restrict__ Wk, const float* __restrict__ bk,
    const float* __restrict__ Wv, const float* __restrict__ bv,
    float* __restrict__ qb, float* __restrict__ kb, float* __restrict__ vb) {
    __shared__ __align__(16) float zsh[64][132];
    __shared__ __align__(16) float wsh[32 * 256];
    const int t = threadIdx.x;
    const int n0 = blockIdx.x * 64;
    const float4* z4 = (const float4*)z;
    #pragma unroll
    for (int q = 0; q < 8; ++q) {
        int idx4 = t + q * 256;                // 2048 float4 = 64 rows x 32
        int row = idx4 >> 5, c4 = idx4 & 31;
        float4 v = make_float4(0.f, 0.f, 0.f, 0.f);
        if (n0 + row < NN) v = z4[(size_t)(n0 + row) * 32 + c4];
        *(float4*)&zsh[row][c4 * 4] = v;
    }
    gemm_one(Wq, bq, qb, 2.0f, zsh, wsh, t, n0);
    gemm_one(Wk, bk, kb, 2.0f, zsh, wsh, t, n0);
    gemm_one(Wv, bv, vb, 1.0f, zsh, wsh, t, n0);
}

// ---------------------------------------------------------------- K2: random features (GEMM form)
__global__ __launch_bounds__(256) void feat_kernel(
    float* __restrict__ qb, float* __restrict__ kb,
    const float* __restrict__ proj, unsigned* __restrict__ gmax,
    unsigned short* __restrict__ qbh) {
    __shared__ __align__(16) float pT[64][68];   // pT[d][m]
    __shared__ __align__(16) float tT[64][68];   // tT[d][n]
    __shared__ float diag_sh[64];
    __shared__ float wmax_sh[4];
    const int t = threadIdx.x;
    const int h = blockIdx.y;
    const int n0 = blockIdx.x * 64;
    const int tx = t & 15, ty = t >> 4;
    const float dn = 0.35355339059327373f;  // 64^-0.25
    const float4* proj4 = (const float4*)proj;
    #pragma unroll
    for (int q = 0; q < 4; ++q) {
        int idx4 = t + q * 256;
        int m = idx4 >> 4, d4 = idx4 & 15;
        float4 v = proj4[m * 16 + d4];
        pT[d4 * 4 + 0][m] = v.x; pT[d4 * 4 + 1][m] = v.y;
        pT[d4 * 4 + 2][m] = v.z; pT[d4 * 4 + 3][m] = v.w;
    }
    #pragma unroll
    for (int pass = 0; pass < 2; ++pass) {
        float* buf = pass ? kb : qb;
        const float4* b4 = (const float4*)buf;
        __syncthreads();
        #pragma unroll
        for (int q = 0; q < 4; ++q) {
            int idx4 = t + q * 256;
            int n = idx4 >> 4, d4 = idx4 & 15;
            float4 v = make_float4(0.f, 0.f, 0.f, 0.f);
            if (n0 + n < NN) v = b4[(n0 + n) * 64 + h * 16 + d4];
            tT[d4 * 4 + 0][n] = v.x * dn; tT[d4 * 4 + 1][n] = v.y * dn;
            tT[d4 * 4 + 2][n] = v.z * dn; tT[d4 * 4 + 3][n] = v.w * dn;
        }
        __syncthreads();
        if (t < 64) {
            float s = 0.f;
            #pragma unroll 8
            for (int d = 0; d < 64; ++d) { float v = tT[d][t]; s += v * v; }
            diag_sh[t] = 0.5f * s;
        }
        __syncthreads();
        float acc[4][4];
        #pragma unroll
        for (int i = 0; i < 4; ++i)
            #pragma unroll
            for (int j = 0; j < 4; ++j) acc[i][j] = 0.f;
        #pragma unroll 8
        for (int d = 0; d < 64; ++d) {
            float4 a = *(const float4*)&tT[d][ty * 4];
            float4 b = *(const float4*)&pT[d][tx * 4];
            float a_[4] = {a.x, a.y, a.z, a.w};
            float b_[4] = {b.x, b.y, b.z, b.w};
            #pragma unroll
            for (int i = 0; i < 4; ++i)
                #pragma unroll
                for (int j = 0; j < 4; ++j) acc[i][j] += a_[i] * b_[j];
        }
        if (pass == 0) {
            #pragma unroll
            for (int i = 0; i < 4; ++i) {
                int n = n0 + ty * 4 + i;
                float mx = fmaxf(fmaxf(acc[i][0], acc[i][1]), fmaxf(acc[i][2], acc[i][3]));
                mx = fmaxf(mx, __shfl_xor(mx, 1, 64));
                mx = fmaxf(mx, __shfl_xor(mx, 2, 64));
                mx = fmaxf(mx, __shfl_xor(mx, 4, 64));
                mx = fmaxf(mx, __shfl_xor(mx, 8, 64));
                if (n < NN) {
                    float dg = diag_sh[ty * 4 + i] + mx;
                    ushort4 u;
                    u.x = f2bf(0.125f * (__expf(acc[i][0] - dg) + 1e-6f));
                    u.y = f2bf(0.125f * (__expf(acc[i][1] - dg) + 1e-6f));
                    u.z = f2bf(0.125f * (__expf(acc[i][2] - dg) + 1e-6f));
                    u.w = f2bf(0.125f * (__expf(acc[i][3] - dg) + 1e-6f));
                    *(ushort4*)&qbh[n * NHD + h * DD + tx * 4] = u;
                }
            }
        } else {
            float km = -3.4e38f;
            #pragma unroll
            for (int i = 0; i < 4; ++i) {
                int n = n0 + ty * 4 + i;
                if (n < NN) {
                    float dg = diag_sh[ty * 4 + i];
                    float4 o;
                    o.x = acc[i][0] - dg; o.y = acc[i][1] - dg;
                    o.z = acc[i][2] - dg; o.w = acc[i][3] - dg;
                    *(float4*)&kb[n * NHD + h * DD + tx * 4] = o;
                    km = fmaxf(km, fmaxf(fmaxf(acc[i][0], acc[i][1]),
                                         fmaxf(acc[i][2], acc[i][3])));
                }
            }
            #pragma unroll
            for (int off = 1; off < 64; off <<= 1) km = fmaxf(km, __shfl_xor(km, off, 64));
            if ((t & 63) == 0) wmax_sh[t >> 6] = km;
            __syncthreads();
            if (t == 0) {
                float m2 = fmaxf(fmaxf(wmax_sh[0], wmax_sh[1]), fmaxf(wmax_sh[2], wmax_sh[3]));
                atomicMax(&gmax[h], f2key(m2));
            }
        }
    }
}

// ---------------------------------------------------------------- K3: kp finalize (float4 + bf16 mirror)
__global__ void kfin_kernel(float* __restrict__ kb, const unsigned* __restrict__ gmax,
                            unsigned short* __restrict__ kbh) {
    int idx = (blockIdx.x * 256 + threadIdx.x) * 4;   // 7,680,000 total elems
    int h = (idx >> 6) & 3;
    float mx = key2f(gmax[h]);
    float4 v = *(float4*)&kb[idx];
    v.x = 0.125f * (__expf(v.x - mx) + 1e-6f);
    v.y = 0.125f * (__expf(v.y - mx) + 1e-6f);
    v.z = 0.125f * (__expf(v.z - mx) + 1e-6f);
    v.w = 0.125f * (__expf(v.w - mx) + 1e-6f);
    *(float4*)&kb[idx] = v;
    ushort4 u;
    u.x = f2bf(v.x); u.y = f2bf(v.y); u.z = f2bf(v.z); u.w = f2bf(v.w);
    *(ushort4*)&kbh[idx] = u;
}

// ---------------------------------------------------------------- K4: kvs partials (6 k, 512 thr, 8 d/thread)
__global__ __launch_bounds__(512) void kvs_kernel(
    const float* __restrict__ kb, const float* __restrict__ vb,
    const float* __restrict__ gum,
    float* __restrict__ kvsp, float* __restrict__ ksp, float* __restrict__ ksump,
    int chunk) {
    __shared__ __align__(16) float k_sh[32 * 64];
    __shared__ __align__(16) float v_sh[32 * 64];
    __shared__ float w_sh[KK][480];
    const int c = blockIdx.x, h = blockIdx.y;
    const int t = threadIdx.x;
    const int lane = t & 63;   // m
    const int wv = t >> 6;     // 0..7, d-group of 8
    const int n0 = c * chunk;
    const int n1 = (n0 + chunk < NN) ? (n0 + chunk) : NN;
    const int lenp = (chunk + 31) & ~31;
    for (int i = t; i < lenp; i += 512) {
        int n = n0 + i;
        bool ok = (n < n1);
        #pragma unroll
        for (int k = 0; k < KK; ++k)
            w_sh[k][i] = ok ? __expf(gum[n * 24 + h * KK + k] * 4.0f) : 0.f;
    }
    float acc[KK][8];
    #pragma unroll
    for (int k = 0; k < KK; ++k)
        #pragma unroll
        for (int i = 0; i < 8; ++i) acc[k][i] = 0.f;
    float ks_acc[KK] = {0.f, 0.f, 0.f, 0.f, 0.f, 0.f};
    float ksum_acc = 0.f;
    const float4* kb4 = (const float4*)kb;
    const float4* vb4 = (const float4*)vb;
    for (int nt = n0; nt < n1; nt += 32) {
        __syncthreads();
        #pragma unroll
        for (int q = 0; q < 2; ++q) {
            int idx4 = t + q * 512;       // 1024 float4 = 32 rows x 32
            int row = idx4 >> 5;
            int wi = idx4 & 31;
            int n = nt + row;
            float4 val = make_float4(0.f, 0.f, 0.f, 0.f);
            if (n < n1)
                val = (wi < 16) ? kb4[n * 64 + h * 16 + wi]
                                : vb4[n * 64 + h * 16 + (wi - 16)];
            if (wi < 16) *(float4*)&k_sh[row * 64 + wi * 4] = val;
            else         *(float4*)&v_sh[row * 64 + (wi - 16) * 4] = val;
        }
        __syncthreads();
        const int bw = nt - n0;
        const int jmax = (n1 - nt < 32) ? (n1 - nt) : 32;
        #pragma unroll 2
        for (int j = 0; j < jmax; ++j) {
            float kpm = k_sh[j * 64 + lane];
            ksum_acc += kpm;
            const float4* v4 = (const float4*)&v_sh[j * 64 + wv * 8];
            float4 vv0 = v4[0], vv1 = v4[1];
            #pragma unroll
            for (int k = 0; k < KK; ++k) {
                float a = kpm * w_sh[k][bw + j];
                ks_acc[k] += a;
                acc[k][0] += a * vv0.x; acc[k][1] += a * vv0.y;
                acc[k][2] += a * vv0.z; acc[k][3] += a * vv0.w;
                acc[k][4] += a * vv1.x; acc[k][5] += a * vv1.y;
                acc[k][6] += a * vv1.z; acc[k][7] += a * vv1.w;
            }
        }
    }
    #pragma unroll
    for (int k = 0; k < KK; ++k) {
        int base = (((c * HH + h) * KK + k) * 64 + lane) * 64 + wv * 8;
        float4* o4 = (float4*)&kvsp[base];
        o4[0] = make_float4(acc[k][0], acc[k][1], acc[k][2], acc[k][3]);
        o4[1] = make_float4(acc[k][4], acc[k][5], acc[k][6], acc[k][7]);
    }
    if (wv == 0) {
        #pragma unroll
        for (int k = 0; k < KK; ++k)
            ksp[((c * HH + h) * KK + k) * 64 + lane] = ks_acc[k];
        ksump[(c * HH + h) * 64 + lane] = ksum_acc;
    }
}

// ---------------------------------------------------------------- K5: reduce partials -> bf16 transposed kvs
__global__ void reduce_kernel(const float* __restrict__ kvsp, const float* __restrict__ ksp,
                              const float* __restrict__ ksump,
                              unsigned short* __restrict__ kvshT, float* __restrict__ kss,
                              float* __restrict__ ksum, int ncs) {
    int idx = blockIdx.x * 256 + threadIdx.x;
    if (idx < 98304) {
        float s = 0.f;
        for (int c = 0; c < ncs; ++c) s += kvsp[c * 98304 + idx];
        // idx = ((h*6+k)*64 + m)*64 + d  ->  kvshT[((h*6+k)*64 + d)*64 + m]
        int d = idx & 63, m = (idx >> 6) & 63, hk = idx >> 12;
        kvshT[(hk * 64 + d) * 64 + m] = f2bf(s);
    } else if (idx < 98304 + 1536) {
        int o = idx - 98304;
        float s = 0.f;
        for (int c = 0; c < ncs; ++c) s += ksp[c * 1536 + o];
        kss[o] = s;
    } else if (idx < 98304 + 1536 + 256) {
        int o = idx - 98304 - 1536;
        float s = 0.f;
        for (int c = 0; c < ncs; ++c) s += ksump[c * 256 + o];
        ksum[o] = s;
    }
}

// ---------------------------------------------------------------- K6: znum via MFMA bf16
// Per block: 64 nodes x 1 head. A = qp bf16 [64n][64m], B = kvsT bf16 [6k*64d][64m],
// both XOR-swizzled ((row&7) granule XOR). z_den/nrm in f32 from bf16 A.
__global__ __launch_bounds__(256) void znum_kernel(
    const unsigned short* __restrict__ qbh, const unsigned short* __restrict__ kvshT,
    const float* __restrict__ kss, const float* __restrict__ ksum,
    float* __restrict__ zout, float* __restrict__ nrm) {
    __shared__ __align__(16) unsigned short qpa[64 * 64];    //  8,192 B
    __shared__ __align__(16) unsigned short bt[6 * 64 * 64]; // 49,152 B
    __shared__ float ks_sh[384];
    __shared__ float ksum_sh[64];
    __shared__ float zdi[64 * 6];
    const int t = threadIdx.x;
    const int h = blockIdx.y;
    const int n0 = blockIdx.x * 64;
    const uint4* qg = (const uint4*)qbh;
    #pragma unroll
    for (int q = 0; q < 2; ++q) {
        int idx = t + q * 256;            // 512 uint4 = 64 rows x 8
        int row = idx >> 3, c8 = idx & 7;
        int n = n0 + row;
        uint4 v = make_uint4(0u, 0u, 0u, 0u);
        if (n < NN) v = qg[n * 32 + h * 8 + c8];
        *(uint4*)&qpa[row * 64 + ((c8 ^ (row & 7)) * 8)] = v;
    }
    const uint4* bg = (const uint4*)kvshT;
    #pragma unroll
    for (int q = 0; q < 12; ++q) {
        int idx = t + q * 256;            // 3072 uint4 = 384 kd-rows x 8
        int kd = idx >> 3, c8 = idx & 7;
        *(uint4*)&bt[kd * 64 + ((c8 ^ (kd & 7)) * 8)] = bg[h * 3072 + idx];
    }
    for (int i = t; i < 384; i += 256) ks_sh[i] = kss[h * 384 + i];
    if (t < 64) ksum_sh[t] = ksum[h * 64 + t];
    __syncthreads();
    // phase 1: z_den inverse + norm (f32 from bf16 qp). 512 work items on 256 threads.
    for (int idx = t; idx < 512; idx += 256) {
        if (idx < 384) {
            int node = idx / 6, k = idx - node * 6;
            int swz = (node & 7) << 3;
            float s = 0.f;
            for (int m = 0; m < 64; ++m)
                s += __uint_as_float((unsigned)qpa[node * 64 + (m ^ swz)] << 16) * ks_sh[k * 64 + m];
            zdi[node * 6 + k] = 1.0f / s;
        } else if (idx < 448) {
            int node = idx - 384;
            int swz = (node & 7) << 3;
            float s = 0.f;
            for (int m = 0; m < 64; ++m)
                s += __uint_as_float((unsigned)qpa[node * 64 + (m ^ swz)] << 16) * ksum_sh[m];
            int n = n0 + node;
            if (n < NN) nrm[n * HH + h] = s;
        }
    }
    __syncthreads();
    // phase 2: MFMA. A: row=lane&15, k=(lane>>4)*8+e. B: col=lane&15, same k. D: col=lane&15, row=(lane>>4)*4+r.
    const int w = t >> 6, lane = t & 63;
    const int lrow = lane & 15, lk = lane >> 4;
    const int arow = w * 16 + lrow;
    const int aswz = (arow & 7) << 3;
    bf16x8 a0 = *(const bf16x8*)&qpa[arow * 64 + ((lk * 8) ^ aswz)];
    bf16x8 a1 = *(const bf16x8*)&qpa[arow * 64 + ((lk * 8 + 32) ^ aswz)];
    const float inv6 = 1.0f / 6.0f;
    #pragma unroll
    for (int dt = 0; dt < 4; ++dt) {
        f32x4 outv = {0.f, 0.f, 0.f, 0.f};
        #pragma unroll
        for (int k = 0; k < KK; ++k) {
            int kd = k * 64 + dt * 16 + lrow;
            int sw = (kd & 7) << 3;
            bf16x8 b0 = *(const bf16x8*)&bt[kd * 64 + ((lk * 8) ^ sw)];
            bf16x8 b1 = *(const bf16x8*)&bt[kd * 64 + ((lk * 8 + 32) ^ sw)];
            f32x4 acc = {0.f, 0.f, 0.f, 0.f};
            acc = __builtin_amdgcn_mfma_f32_16x16x32_bf16(a0, b0, acc, 0, 0, 0);
            acc = __builtin_amdgcn_mfma_f32_16x16x32_bf16(a1, b1, acc, 0, 0, 0);
            #pragma unroll
            for (int r = 0; r < 4; ++r)
                outv[r] += zdi[(w * 16 + lk * 4 + r) * 6 + k] * acc[r];
        }
        #pragma unroll
        for (int r = 0; r < 4; ++r) {
            int n = n0 + w * 16 + lk * 4 + r;
            if (n < NN) zout[(size_t)n * NHD + h * DD + dt * 16 + lrow] = outv[r] * inv6;
        }
    }
}

// ---------------------------------------------------------------- K7: output projection (f32 out)
__global__ __launch_bounds__(256) void outproj_kernel(
    const float* __restrict__ zout, const float* __restrict__ Wo,
    const float* __restrict__ bo, float* __restrict__ out) {
    __shared__ float zsh[16][NHD];
    const int t = threadIdx.x;
    const int n0 = blockIdx.x * 16;
    #pragma unroll
    for (int q = 0; q < 16; ++q) {
        int idx = t + q * 256;
        int nn2 = idx >> 8, r = idx & 255;
        zsh[nn2][r] = zout[(n0 + nn2) * NHD + r];
    }
    __syncthreads();
    const int c = t & 63, g = t >> 6;
    float acc[4];
    #pragma unroll
    for (int i = 0; i < 4; ++i) acc[i] = bo[c];
    for (int r = 0; r < 256; ++r) {
        float w = Wo[r * 64 + c];
        #pragma unroll
        for (int i = 0; i < 4; ++i) acc[i] += zsh[g + 4 * i][r] * w;
    }
    #pragma unroll
    for (int i = 0; i < 4; ++i)
        out[(n0 + g + 4 * i) * 64 + c] = acc[i];
}

// ---------------------------------------------------------------- K8: edges, bf16 gather (8 edges/block)
__global__ __launch_bounds__(256) void edge_bf16_kernel(
    const unsigned short* __restrict__ qbh, const unsigned short* __restrict__ kbh,
    const int* __restrict__ ei, const float* __restrict__ nrm,
    float* __restrict__ out) {
    const int t = threadIdx.x;
    const int lane5 = t & 31;
    const int e = blockIdx.x * 8 + (t >> 5);
    const int s = ei[e], d = ei[EE + e];
    const uint4* q4 = (const uint4*)qbh;
    const uint4* k4 = (const uint4*)kbh;
    uint4 qv = q4[d * 32 + lane5];
    uint4 kv = k4[s * 32 + lane5];
    const unsigned short* qs = (const unsigned short*)&qv;
    const unsigned short* ks = (const unsigned short*)&kv;
    float p = 0.f;
    #pragma unroll
    for (int i = 0; i < 8; ++i) {
        float qf = __uint_as_float((unsigned)qs[i] << 16);
        float kf = __uint_as_float((unsigned)ks[i] << 16);
        p += qf * kf;
    }
    p += __shfl_xor(p, 1, 64);
    p += __shfl_xor(p, 2, 64);
    p += __shfl_xor(p, 4, 64);
    if ((lane5 & 7) == 0) {
        int h = lane5 >> 3;
        out[ZOFF + e * 4 + h] = p / nrm[d * HH + h];
    }
}

// ---------------------------------------------------------------- launch
extern "C" void kernel_launch(void* const* d_in, const int* in_sizes, int n_in,
                              void* d_out, int out_size, void* d_ws, size_t ws_size,
                              hipStream_t stream) {
    (void)in_sizes; (void)n_in; (void)out_size;
    const float* z  = (const float*)d_in[0];
    const float* Wq = (const float*)d_in[1];
    const float* bq = (const float*)d_in[2];
    const float* Wk = (const float*)d_in[3];
    const float* bk = (const float*)d_in[4];
    const float* Wv = (const float*)d_in[5];
    const float* bv = (const float*)d_in[6];
    const float* Wo = (const float*)d_in[7];
    const float* bo = (const float*)d_in[8];
    const float* proj = (const float*)d_in[9];
    const float* gum  = (const float*)d_in[10];
    const int*   ei   = (const int*)d_in[11];
    float* out = (float*)d_out;
    float* ws = (float*)d_ws;

    const size_t fs = ws_size / 4;
    int ncs;
    if      (fs >= 43752388) ncs = 128;
    else if (fs >= 37346244) ncs = 64;
    else return;
    const int chunk = (NN + ncs - 1) / ncs;   // 235 or 469

    float* qb    = ws;                  // 7,680,000 (raw q; qp lives only in qbh)
    float* kb    = ws + 7680000;        // 7,680,000
    float* vb    = ws + 15360000;       // 7,680,000 (reused as zout after kvs)
    float* zout  = vb;
    unsigned short* kvshT = (unsigned short*)(ws + 23040000);  // 98,304 bf16 (49,152 fl)
    float* kss   = ws + 23138304;       // 1,536
    float* ksum  = ws + 23139840;       // 256
    float* nrm   = ws + 23140096;       // 120,000
    unsigned* gmax = (unsigned*)(ws + 23260096);  // 4
    float* p = ws + 23260100;
    unsigned short* qbh = (unsigned short*)p;              // 7,680,000 bf16
    unsigned short* kbh = (unsigned short*)(p + 3840000);  // 7,680,000 bf16
    p += 7680000;
    float* ksp   = p;                           // ncs*1536
    float* ksump = ksp + (size_t)ncs * 1536;    // ncs*256
    float* kvsp  = ksump + (size_t)ncs * 256;   // ncs*98304

    init_kernel<<<1, 64, 0, stream>>>(gmax);
    qkv_kernel<<<469, 256, 0, stream>>>(z, Wq, bq, Wk, bk, Wv, bv, qb, kb, vb);
    feat_kernel<<<dim3(469, HH), 256, 0, stream>>>(qb, kb, proj, gmax, qbh);
    kfin_kernel<<<7500, 256, 0, stream>>>(kb, gmax, kbh);
    kvs_kernel<<<dim3(ncs, HH), 512, 0, stream>>>(kb, vb, gum, kvsp, ksp, ksump, chunk);
    reduce_kernel<<<392, 256, 0, stream>>>(kvsp, ksp, ksump, kvshT, kss, ksum, ncs);
    znum_kernel<<<dim3(469, HH), 256, 0, stream>>>(qbh, kvshT, kss, ksum, zout, nrm);
    outproj_kernel<<<1875, 256, 0, stream>>>(zout, Wo, bo, out);
    edge_bf16_kernel<<<60000, 256, 0, stream>>>(qbh, kbh, ei, nrm, out);
}

// Round 11
// 345.601 us; speedup vs baseline: 1.3908x; 1.2118x over previous
//
#include <hip/hip_runtime.h>
#include <hip/hip_bf16.h>

#define NN   30000
#define DIN  128
#define NHD  256      // H*D
#define HH   4
#define DD   64
#define MM   64
#define KK   6
#define EE   480000
#define ZOFF 1920000  // 30000*64
#define NCS   125
#define CHUNK 240
#define PITCH  30208   // padded bf16 elems per row of kbhT/vbhT
#define PITCH4 3776    // uint4 per row

typedef __attribute__((ext_vector_type(8))) short bf16x8;
typedef __attribute__((ext_vector_type(4))) float f32x4;

__device__ __forceinline__ unsigned f2key(float f) {
    unsigned u = __float_as_uint(f);
    return (u & 0x80000000u) ? ~u : (u | 0x80000000u);
}
__device__ __forceinline__ float key2f(unsigned k) {
    return __uint_as_float((k & 0x80000000u) ? (k ^ 0x80000000u) : ~k);
}
__device__ __forceinline__ unsigned short f2bf(float f) {   // RNE
    unsigned u = __float_as_uint(f);
    unsigned r = ((u >> 16) & 1u) + 0x7fffu;
    return (unsigned short)((u + r) >> 16);
}
__device__ __forceinline__ float bf2f(unsigned short u) {
    return __uint_as_float((unsigned)u << 16);
}

// ---------------------------------------------------------------- init
__global__ void init_kernel(unsigned* gmax) {
    if (threadIdx.x < HH) gmax[threadIdx.x] = 0u;
}

// ---------------------------------------------------------------- K1: qkv GEMM
__device__ __forceinline__ void gemm_one(const float* __restrict__ W,
                                         const float* __restrict__ b,
                                         float* __restrict__ O, float sc,
                                         const float (*zsh)[132], float* wsh,
                                         int t, int n0) {
    const int tx = t & 15, ty = t >> 4;
    float4 acc[4][4];
    #pragma unroll
    for (int i = 0; i < 4; ++i)
        #pragma unroll
        for (int g = 0; g < 4; ++g) acc[i][g] = make_float4(0.f, 0.f, 0.f, 0.f);
    const float4* W4 = (const float4*)W;
    for (int rt = 0; rt < 4; ++rt) {
        __syncthreads();
        #pragma unroll
        for (int q = 0; q < 8; ++q) {
            int idx4 = t + q * 256;
            *(float4*)&wsh[idx4 * 4] = W4[rt * 2048 + idx4];
        }
        __syncthreads();
        #pragma unroll 4
        for (int j = 0; j < 32; ++j) {
            const int col = rt * 32 + j;
            float a0 = zsh[ty][col];
            float a1 = zsh[ty + 16][col];
            float a2 = zsh[ty + 32][col];
            float a3 = zsh[ty + 48][col];
            #pragma unroll
            for (int g = 0; g < 4; ++g) {
                float4 bb = *(const float4*)&wsh[j * 256 + g * 64 + tx * 4];
                acc[0][g].x += a0 * bb.x; acc[0][g].y += a0 * bb.y;
                acc[0][g].z += a0 * bb.z; acc[0][g].w += a0 * bb.w;
                acc[1][g].x += a1 * bb.x; acc[1][g].y += a1 * bb.y;
                acc[1][g].z += a1 * bb.z; acc[1][g].w += a1 * bb.w;
                acc[2][g].x += a2 * bb.x; acc[2][g].y += a2 * bb.y;
                acc[2][g].z += a2 * bb.z; acc[2][g].w += a2 * bb.w;
                acc[3][g].x += a3 * bb.x; acc[3][g].y += a3 * bb.y;
                acc[3][g].z += a3 * bb.z; acc[3][g].w += a3 * bb.w;
            }
        }
    }
    #pragma unroll
    for (int g = 0; g < 4; ++g) {
        float4 bias = *(const float4*)&b[g * 64 + tx * 4];
        #pragma unroll
        for (int i = 0; i < 4; ++i) {
            int n = n0 + ty + i * 16;
            if (n < NN) {
                float4 o;
                o.x = (acc[i][g].x + bias.x) * sc;
                o.y = (acc[i][g].y + bias.y) * sc;
                o.z = (acc[i][g].z + bias.z) * sc;
                o.w = (acc[i][g].w + bias.w) * sc;
                *(float4*)&O[(size_t)n * NHD + g * 64 + tx * 4] = o;
            }
        }
    }
}

__global__ __launch_bounds__(256) void qkv_kernel(
    const float* __restrict__ z,
    const float* __restrict__ Wq, const float* __restrict__ bq,
    const float* __restrict__ Wk, const float* __restrict__ bk,
    const float* __restrict__ Wv, const float* __restrict__ bv,
    float* __restrict__ qb, float* __restrict__ kb, float* __restrict__ vb) {
    __shared__ __align__(16) float zsh[64][132];
    __shared__ __align__(16) float wsh[32 * 256];
    const int t = threadIdx.x;
    const int n0 = blockIdx.x * 64;
    const float4* z4 = (const float4*)z;
    #pragma unroll
    for (int q = 0; q < 8; ++q) {
        int idx4 = t + q * 256;
        int row = idx4 >> 5, c4 = idx4 & 31;
        float4 v = make_float4(0.f, 0.f, 0.f, 0.f);
        if (n0 + row < NN) v = z4[(size_t)(n0 + row) * 32 + c4];
        *(float4*)&zsh[row][c4 * 4] = v;
    }
    gemm_one(Wq, bq, qb, 2.0f, zsh, wsh, t, n0);
    gemm_one(Wk, bk, kb, 2.0f, zsh, wsh, t, n0);
    gemm_one(Wv, bv, vb, 1.0f, zsh, wsh, t, n0);
}

// ---------------------------------------------------------------- K2: random features (GEMM form)
__global__ __launch_bounds__(256) void feat_kernel(
    float* __restrict__ qb, float* __restrict__ kb,
    const float* __restrict__ proj, unsigned* __restrict__ gmax,
    unsigned short* __restrict__ qbh) {
    __shared__ __align__(16) float pT[64][68];
    __shared__ __align__(16) float tT[64][68];
    __shared__ float diag_sh[64];
    __shared__ float wmax_sh[4];
    const int t = threadIdx.x;
    const int h = blockIdx.y;
    const int n0 = blockIdx.x * 64;
    const int tx = t & 15, ty = t >> 4;
    const float dn = 0.35355339059327373f;
    const float4* proj4 = (const float4*)proj;
    #pragma unroll
    for (int q = 0; q < 4; ++q) {
        int idx4 = t + q * 256;
        int m = idx4 >> 4, d4 = idx4 & 15;
        float4 v = proj4[m * 16 + d4];
        pT[d4 * 4 + 0][m] = v.x; pT[d4 * 4 + 1][m] = v.y;
        pT[d4 * 4 + 2][m] = v.z; pT[d4 * 4 + 3][m] = v.w;
    }
    #pragma unroll
    for (int pass = 0; pass < 2; ++pass) {
        float* buf = pass ? kb : qb;
        const float4* b4 = (const float4*)buf;
        __syncthreads();
        #pragma unroll
        for (int q = 0; q < 4; ++q) {
            int idx4 = t + q * 256;
            int n = idx4 >> 4, d4 = idx4 & 15;
            float4 v = make_float4(0.f, 0.f, 0.f, 0.f);
            if (n0 + n < NN) v = b4[(n0 + n) * 64 + h * 16 + d4];
            tT[d4 * 4 + 0][n] = v.x * dn; tT[d4 * 4 + 1][n] = v.y * dn;
            tT[d4 * 4 + 2][n] = v.z * dn; tT[d4 * 4 + 3][n] = v.w * dn;
        }
        __syncthreads();
        if (t < 64) {
            float s = 0.f;
            #pragma unroll 8
            for (int d = 0; d < 64; ++d) { float v = tT[d][t]; s += v * v; }
            diag_sh[t] = 0.5f * s;
        }
        __syncthreads();
        float acc[4][4];
        #pragma unroll
        for (int i = 0; i < 4; ++i)
            #pragma unroll
            for (int j = 0; j < 4; ++j) acc[i][j] = 0.f;
        #pragma unroll 8
        for (int d = 0; d < 64; ++d) {
            float4 a = *(const float4*)&tT[d][ty * 4];
            float4 b = *(const float4*)&pT[d][tx * 4];
            float a_[4] = {a.x, a.y, a.z, a.w};
            float b_[4] = {b.x, b.y, b.z, b.w};
            #pragma unroll
            for (int i = 0; i < 4; ++i)
                #pragma unroll
                for (int j = 0; j < 4; ++j) acc[i][j] += a_[i] * b_[j];
        }
        if (pass == 0) {
            #pragma unroll
            for (int i = 0; i < 4; ++i) {
                int n = n0 + ty * 4 + i;
                float mx = fmaxf(fmaxf(acc[i][0], acc[i][1]), fmaxf(acc[i][2], acc[i][3]));
                mx = fmaxf(mx, __shfl_xor(mx, 1, 64));
                mx = fmaxf(mx, __shfl_xor(mx, 2, 64));
                mx = fmaxf(mx, __shfl_xor(mx, 4, 64));
                mx = fmaxf(mx, __shfl_xor(mx, 8, 64));
                if (n < NN) {
                    float dg = diag_sh[ty * 4 + i] + mx;
                    ushort4 u;
                    u.x = f2bf(0.125f * (__expf(acc[i][0] - dg) + 1e-6f));
                    u.y = f2bf(0.125f * (__expf(acc[i][1] - dg) + 1e-6f));
                    u.z = f2bf(0.125f * (__expf(acc[i][2] - dg) + 1e-6f));
                    u.w = f2bf(0.125f * (__expf(acc[i][3] - dg) + 1e-6f));
                    *(ushort4*)&qbh[n * NHD + h * DD + tx * 4] = u;
                }
            }
        } else {
            float km = -3.4e38f;
            #pragma unroll
            for (int i = 0; i < 4; ++i) {
                int n = n0 + ty * 4 + i;
                if (n < NN) {
                    float dg = diag_sh[ty * 4 + i];
                    float4 o;
                    o.x = acc[i][0] - dg; o.y = acc[i][1] - dg;
                    o.z = acc[i][2] - dg; o.w = acc[i][3] - dg;
                    *(float4*)&kb[n * NHD + h * DD + tx * 4] = o;
                    km = fmaxf(km, fmaxf(fmaxf(acc[i][0], acc[i][1]),
                                         fmaxf(acc[i][2], acc[i][3])));
                }
            }
            #pragma unroll
            for (int off = 1; off < 64; off <<= 1) km = fmaxf(km, __shfl_xor(km, off, 64));
            if ((t & 63) == 0) wmax_sh[t >> 6] = km;
            __syncthreads();
            if (t == 0) {
                float m2 = fmaxf(fmaxf(wmax_sh[0], wmax_sh[1]), fmaxf(wmax_sh[2], wmax_sh[3]));
                atomicMax(&gmax[h], f2key(m2));
            }
        }
    }
}

// ---------------------------------------------------------------- K3: kp finalize (float4 + bf16 mirror)
__global__ void kfin_kernel(float* __restrict__ kb, const unsigned* __restrict__ gmax,
                            unsigned short* __restrict__ kbh) {
    int idx = (blockIdx.x * 256 + threadIdx.x) * 4;
    int h = (idx >> 6) & 3;
    float mx = key2f(gmax[h]);
    float4 v = *(float4*)&kb[idx];
    v.x = 0.125f * (__expf(v.x - mx) + 1e-6f);
    v.y = 0.125f * (__expf(v.y - mx) + 1e-6f);
    v.z = 0.125f * (__expf(v.z - mx) + 1e-6f);
    v.w = 0.125f * (__expf(v.w - mx) + 1e-6f);
    *(float4*)&kb[idx] = v;
    ushort4 u;
    u.x = f2bf(v.x); u.y = f2bf(v.y); u.z = f2bf(v.z); u.w = f2bf(v.w);
    *(ushort4*)&kbh[idx] = u;
}

// ---------------------------------------------------------------- K3b: transpose f32 [n][h*64+c] -> bf16 [h*64+c][n]
__global__ __launch_bounds__(256) void transp_kernel(
    const float* __restrict__ src, unsigned short* __restrict__ dst) {
    __shared__ unsigned short tl[64][72];
    const int t = threadIdx.x;
    const int nt = blockIdx.x * 64;
    const int h = blockIdx.y;
    const float4* s4 = (const float4*)src;
    #pragma unroll
    for (int it = 0; it < 4; ++it) {
        int idx = t + it * 256;
        int c4 = idx & 15, n = idx >> 4;
        float4 v = make_float4(0.f, 0.f, 0.f, 0.f);
        if (nt + n < NN) v = s4[(size_t)(nt + n) * 64 + h * 16 + c4];
        tl[c4 * 4 + 0][n] = f2bf(v.x);
        tl[c4 * 4 + 1][n] = f2bf(v.y);
        tl[c4 * 4 + 2][n] = f2bf(v.z);
        tl[c4 * 4 + 3][n] = f2bf(v.w);
    }
    __syncthreads();
    uint4* d4 = (uint4*)dst;
    #pragma unroll
    for (int it = 0; it < 2; ++it) {
        int idx = t + it * 256;
        int g = idx & 7, m = idx >> 3;
        d4[(size_t)(h * 64 + m) * PITCH4 + (nt >> 3) + g] = *(uint4*)&tl[m][g * 8];
    }
}

// ---------------------------------------------------------------- K4: kvs via MFMA bf16
// Per block (c,h): chunk=240 n-rows, 4 subtiles of 64. A=vT[d][n], B=kpwT[m][n],
// both LDS bf16 with granule-XOR swizzle (same scheme as znum, HW-validated).
// Output bf16 partials [c][h][k][d][m] (already transposed for znum).
__global__ __launch_bounds__(512) void kvs_kernel(
    const unsigned short* __restrict__ kbhT, const unsigned short* __restrict__ vbhT,
    const float* __restrict__ gum,
    unsigned short* __restrict__ kvsp, float* __restrict__ ksp, float* __restrict__ ksump) {
    __shared__ __align__(16) unsigned short kpa[64 * 64];
    __shared__ __align__(16) unsigned short va [64 * 64];
    __shared__ __align__(16) unsigned short kpwa[64 * 64];
    __shared__ float w_sh[KK][256];
    const int c = blockIdx.x, h = blockIdx.y;
    const int t = threadIdx.x;
    const int n0 = c * CHUNK;
    const int n1 = n0 + CHUNK;
    for (int i = t; i < 256; i += 512) {
        int n = n0 + i;
        bool ok = (i < CHUNK);
        #pragma unroll
        for (int k = 0; k < KK; ++k)
            w_sh[k][i] = ok ? __expf(gum[n * 24 + h * KK + k] * 4.0f) : 0.f;
    }
    const int m_ = t >> 3, g_ = t & 7;
    const int w = t >> 6, lane = t & 63, lrow = lane & 15, lk = lane >> 4;
    const int ds = w & 3, mh = w >> 2;
    const int arow = ds * 16 + lrow;
    f32x4 acc[KK][2];
    #pragma unroll
    for (int k = 0; k < KK; ++k) {
        acc[k][0] = (f32x4){0.f, 0.f, 0.f, 0.f};
        acc[k][1] = (f32x4){0.f, 0.f, 0.f, 0.f};
    }
    float ks_acc[KK] = {0.f, 0.f, 0.f, 0.f, 0.f, 0.f};
    float ksum_acc = 0.f;
    const uint4* kT4 = (const uint4*)kbhT;
    const uint4* vT4 = (const uint4*)vbhT;
    #pragma unroll
    for (int s = 0; s < 4; ++s) {
        const int nb = n0 + s * 64;
        __syncthreads();   // prior subtile's LDS reads complete
        uint4 kvv = kT4[(size_t)(h * 64 + m_) * PITCH4 + (nb >> 3) + g_];
        uint4 vvv = vT4[(size_t)(h * 64 + m_) * PITCH4 + (nb >> 3) + g_];
        const int slot = g_ ^ (m_ & 7);
        *(uint4*)&kpa[m_ * 64 + slot * 8] = kvv;
        *(uint4*)&va [m_ * 64 + slot * 8] = vvv;
        // ksum partial (masked to valid chunk rows); convert kp granule once
        float kf[8];
        {
            const unsigned short* ke = (const unsigned short*)&kvv;
            float sl = 0.f;
            int nbase = nb + g_ * 8;
            #pragma unroll
            for (int e = 0; e < 8; ++e) {
                kf[e] = bf2f(ke[e]);
                if (nbase + e < n1) sl += kf[e];
            }
            sl += __shfl_xor(sl, 1, 64);
            sl += __shfl_xor(sl, 2, 64);
            sl += __shfl_xor(sl, 4, 64);
            if (g_ == 0) ksum_acc += sl;
        }
        __syncthreads();   // kpa/va staged
        bf16x8 a0 = *(const bf16x8*)&va[arow * 64 + ((lk ^ (arow & 7)) * 8)];
        bf16x8 a1 = *(const bf16x8*)&va[arow * 64 + (((lk + 4) ^ (arow & 7)) * 8)];
        const int bw = s * 64;
        const int gg = g_ ^ (m_ & 7);   // actual n-granule this thread staged/builds
        #pragma unroll
        for (int k = 0; k < KK; ++k) {
            {   // build kpw = kp * w_k  (bf16), accumulate ks
                unsigned short ov[8];
                float sl = 0.f;
                #pragma unroll
                for (int e = 0; e < 8; ++e) {
                    float p = kf[e] * w_sh[k][bw + gg * 8 + e];
                    sl += p;
                    ov[e] = f2bf(p);
                }
                *(uint4*)&kpwa[m_ * 64 + g_ * 8] = *(uint4*)ov;
                sl += __shfl_xor(sl, 1, 64);
                sl += __shfl_xor(sl, 2, 64);
                sl += __shfl_xor(sl, 4, 64);
                if (g_ == 0) ks_acc[k] += sl;
            }
            __syncthreads();   // kpwa ready
            #pragma unroll
            for (int mt = 0; mt < 2; ++mt) {
                int m = (mh * 2 + mt) * 16 + lrow;
                bf16x8 b0 = *(const bf16x8*)&kpwa[m * 64 + ((lk ^ (m & 7)) * 8)];
                bf16x8 b1 = *(const bf16x8*)&kpwa[m * 64 + (((lk + 4) ^ (m & 7)) * 8)];
                acc[k][mt] = __builtin_amdgcn_mfma_f32_16x16x32_bf16(a0, b0, acc[k][mt], 0, 0, 0);
                acc[k][mt] = __builtin_amdgcn_mfma_f32_16x16x32_bf16(a1, b1, acc[k][mt], 0, 0, 0);
            }
            __syncthreads();   // kpwa consumed before next k overwrites
        }
    }
    const size_t cb = (size_t)(c * HH + h) * KK;
    #pragma unroll
    for (int k = 0; k < KK; ++k)
        #pragma unroll
        for (int mt = 0; mt < 2; ++mt) {
            int m = (mh * 2 + mt) * 16 + lrow;
            #pragma unroll
            for (int r = 0; r < 4; ++r) {
                int d = ds * 16 + lk * 4 + r;
                kvsp[(cb + k) * 4096 + d * 64 + m] = f2bf(acc[k][mt][r]);
            }
        }
    if (g_ == 0) {
        #pragma unroll
        for (int k = 0; k < KK; ++k)
            ksp[(cb + k) * 64 + m_] = ks_acc[k];
        ksump[(size_t)(c * HH + h) * 64 + m_] = ksum_acc;
    }
}

// ---------------------------------------------------------------- K5: reduce bf16 partials -> kvshT, f32 ks/ksum
__global__ void reduce_kernel(const unsigned short* __restrict__ kvsp,
                              const float* __restrict__ ksp, const float* __restrict__ ksump,
                              unsigned short* __restrict__ kvshT, float* __restrict__ kss,
                              float* __restrict__ ksum) {
    int idx = blockIdx.x * 256 + threadIdx.x;
    if (idx < 98304) {
        float s = 0.f;
        for (int c = 0; c < NCS; ++c) s += bf2f(kvsp[c * 98304 + idx]);
        kvshT[idx] = f2bf(s);   // layout already [h][k][d][m]
    } else if (idx < 98304 + 1536) {
        int o = idx - 98304;
        float s = 0.f;
        for (int c = 0; c < NCS; ++c) s += ksp[c * 1536 + o];
        kss[o] = s;
    } else if (idx < 98304 + 1536 + 256) {
        int o = idx - 98304 - 1536;
        float s = 0.f;
        for (int c = 0; c < NCS; ++c) s += ksump[c * 256 + o];
        ksum[o] = s;
    }
}

// ---------------------------------------------------------------- K6: znum via MFMA bf16 (proven)
__global__ __launch_bounds__(256) void znum_kernel(
    const unsigned short* __restrict__ qbh, const unsigned short* __restrict__ kvshT,
    const float* __restrict__ kss, const float* __restrict__ ksum,
    float* __restrict__ zout, float* __restrict__ nrm) {
    __shared__ __align__(16) unsigned short qpa[64 * 64];
    __shared__ __align__(16) unsigned short bt[6 * 64 * 64];
    __shared__ float ks_sh[384];
    __shared__ float ksum_sh[64];
    __shared__ float zdi[64 * 6];
    const int t = threadIdx.x;
    const int h = blockIdx.y;
    const int n0 = blockIdx.x * 64;
    const uint4* qg = (const uint4*)qbh;
    #pragma unroll
    for (int q = 0; q < 2; ++q) {
        int idx = t + q * 256;
        int row = idx >> 3, c8 = idx & 7;
        int n = n0 + row;
        uint4 v = make_uint4(0u, 0u, 0u, 0u);
        if (n < NN) v = qg[n * 32 + h * 8 + c8];
        *(uint4*)&qpa[row * 64 + ((c8 ^ (row & 7)) * 8)] = v;
    }
    const uint4* bg = (const uint4*)kvshT;
    #pragma unroll
    for (int q = 0; q < 12; ++q) {
        int idx = t + q * 256;
        int kd = idx >> 3, c8 = idx & 7;
        *(uint4*)&bt[kd * 64 + ((c8 ^ (kd & 7)) * 8)] = bg[h * 3072 + idx];
    }
    for (int i = t; i < 384; i += 256) ks_sh[i] = kss[h * 384 + i];
    if (t < 64) ksum_sh[t] = ksum[h * 64 + t];
    __syncthreads();
    for (int idx = t; idx < 512; idx += 256) {
        if (idx < 384) {
            int node = idx / 6, k = idx - node * 6;
            int swz = (node & 7) << 3;
            float s = 0.f;
            for (int m = 0; m < 64; ++m)
                s += bf2f(qpa[node * 64 + (m ^ swz)]) * ks_sh[k * 64 + m];
            zdi[node * 6 + k] = 1.0f / s;
        } else if (idx < 448) {
            int node = idx - 384;
            int swz = (node & 7) << 3;
            float s = 0.f;
            for (int m = 0; m < 64; ++m)
                s += bf2f(qpa[node * 64 + (m ^ swz)]) * ksum_sh[m];
            int n = n0 + node;
            if (n < NN) nrm[n * HH + h] = s;
        }
    }
    __syncthreads();
    const int w = t >> 6, lane = t & 63;
    const int lrow = lane & 15, lk = lane >> 4;
    const int arow = w * 16 + lrow;
    const int aswz = (arow & 7) << 3;
    bf16x8 a0 = *(const bf16x8*)&qpa[arow * 64 + ((lk * 8) ^ aswz)];
    bf16x8 a1 = *(const bf16x8*)&qpa[arow * 64 + ((lk * 8 + 32) ^ aswz)];
    const float inv6 = 1.0f / 6.0f;
    #pragma unroll
    for (int dt = 0; dt < 4; ++dt) {
        f32x4 outv = {0.f, 0.f, 0.f, 0.f};
        #pragma unroll
        for (int k = 0; k < KK; ++k) {
            int kd = k * 64 + dt * 16 + lrow;
            int sw = (kd & 7) << 3;
            bf16x8 b0 = *(const bf16x8*)&bt[kd * 64 + ((lk * 8) ^ sw)];
            bf16x8 b1 = *(const bf16x8*)&bt[kd * 64 + ((lk * 8 + 32) ^ sw)];
            f32x4 acc = {0.f, 0.f, 0.f, 0.f};
            acc = __builtin_amdgcn_mfma_f32_16x16x32_bf16(a0, b0, acc, 0, 0, 0);
            acc = __builtin_amdgcn_mfma_f32_16x16x32_bf16(a1, b1, acc, 0, 0, 0);
            #pragma unroll
            for (int r = 0; r < 4; ++r)
                outv[r] += zdi[(w * 16 + lk * 4 + r) * 6 + k] * acc[r];
        }
        #pragma unroll
        for (int r = 0; r < 4; ++r) {
            int n = n0 + w * 16 + lk * 4 + r;
            if (n < NN) zout[(size_t)n * NHD + h * DD + dt * 16 + lrow] = outv[r] * inv6;
        }
    }
}

// ---------------------------------------------------------------- K7: output projection (f32 out)
__global__ __launch_bounds__(256) void outproj_kernel(
    const float* __restrict__ zout, const float* __restrict__ Wo,
    const float* __restrict__ bo, float* __restrict__ out) {
    __shared__ float zsh[16][NHD];
    const int t = threadIdx.x;
    const int n0 = blockIdx.x * 16;
    #pragma unroll
    for (int q = 0; q < 16; ++q) {
        int idx = t + q * 256;
        int nn2 = idx >> 8, r = idx & 255;
        zsh[nn2][r] = zout[(n0 + nn2) * NHD + r];
    }
    __syncthreads();
    const int c = t & 63, g = t >> 6;
    float acc[4];
    #pragma unroll
    for (int i = 0; i < 4; ++i) acc[i] = bo[c];
    for (int r = 0; r < 256; ++r) {
        float w = Wo[r * 64 + c];
        #pragma unroll
        for (int i = 0; i < 4; ++i) acc[i] += zsh[g + 4 * i][r] * w;
    }
    #pragma unroll
    for (int i = 0; i < 4; ++i)
        out[(n0 + g + 4 * i) * 64 + c] = acc[i];
}

// ---------------------------------------------------------------- K8: edges, bf16 gather
__global__ __launch_bounds__(256) void edge_bf16_kernel(
    const unsigned short* __restrict__ qbh, const unsigned short* __restrict__ kbh,
    const int* __restrict__ ei, const float* __restrict__ nrm,
    float* __restrict__ out) {
    const int t = threadIdx.x;
    const int lane5 = t & 31;
    const int e = blockIdx.x * 8 + (t >> 5);
    const int s = ei[e], d = ei[EE + e];
    const uint4* q4 = (const uint4*)qbh;
    const uint4* k4 = (const uint4*)kbh;
    uint4 qv = q4[d * 32 + lane5];
    uint4 kv = k4[s * 32 + lane5];
    const unsigned short* qs = (const unsigned short*)&qv;
    const unsigned short* ks = (const unsigned short*)&kv;
    float p = 0.f;
    #pragma unroll
    for (int i = 0; i < 8; ++i) p += bf2f(qs[i]) * bf2f(ks[i]);
    p += __shfl_xor(p, 1, 64);
    p += __shfl_xor(p, 2, 64);
    p += __shfl_xor(p, 4, 64);
    if ((lane5 & 7) == 0) {
        int h = lane5 >> 3;
        out[ZOFF + e * 4 + h] = p / nrm[d * HH + h];
    }
}

// ---------------------------------------------------------------- launch
extern "C" void kernel_launch(void* const* d_in, const int* in_sizes, int n_in,
                              void* d_out, int out_size, void* d_ws, size_t ws_size,
                              hipStream_t stream) {
    (void)in_sizes; (void)n_in; (void)out_size;
    const float* z  = (const float*)d_in[0];
    const float* Wq = (const float*)d_in[1];
    const float* bq = (const float*)d_in[2];
    const float* Wk = (const float*)d_in[3];
    const float* bk = (const float*)d_in[4];
    const float* Wv = (const float*)d_in[5];
    const float* bv = (const float*)d_in[6];
    const float* Wo = (const float*)d_in[7];
    const float* bo = (const float*)d_in[8];
    const float* proj = (const float*)d_in[9];
    const float* gum  = (const float*)d_in[10];
    const int*   ei   = (const int*)d_in[11];
    float* out = (float*)d_out;
    float* ws = (float*)d_ws;

    // total floats: 23,260,100 + qbh/kbh 7,680,000 + kbhT/vbhT 7,733,248 = 38,673,348
    if (ws_size / 4 < (size_t)38673348) return;

    float* qb    = ws;                  // raw q; region reused for kvs partials after feat
    float* kb    = ws + 7680000;
    float* vb    = ws + 15360000;       // reused as zout
    float* zout  = vb;
    unsigned short* kvshT = (unsigned short*)(ws + 23040000);  // 98,304 bf16
    float* kss   = ws + 23138304;       // 1,536
    float* ksum  = ws + 23139840;       // 256
    float* nrm   = ws + 23140096;       // 120,000
    unsigned* gmax = (unsigned*)(ws + 23260096);  // 4
    unsigned short* qbh = (unsigned short*)(ws + 23260100);    // 7.68M bf16
    unsigned short* kbh = (unsigned short*)(ws + 27100100);    // 7.68M bf16
    unsigned short* kbhT = (unsigned short*)(ws + 30940100);   // 256*30208 bf16
    unsigned short* vbhT = (unsigned short*)(ws + 34806724);   // 256*30208 bf16
    // partials alias qb (dead after feat):
    float* ksp   = ws;                              // 125*1536
    float* ksump = ws + 192000;                     // 125*256
    unsigned short* kvsp = (unsigned short*)(ws + 224000);  // 125*98304 bf16

    init_kernel<<<1, 64, 0, stream>>>(gmax);
    qkv_kernel<<<469, 256, 0, stream>>>(z, Wq, bq, Wk, bk, Wv, bv, qb, kb, vb);
    feat_kernel<<<dim3(469, HH), 256, 0, stream>>>(qb, kb, proj, gmax, qbh);
    kfin_kernel<<<7500, 256, 0, stream>>>(kb, gmax, kbh);
    transp_kernel<<<dim3(472, HH), 256, 0, stream>>>(kb, kbhT);
    transp_kernel<<<dim3(472, HH), 256, 0, stream>>>(vb, vbhT);
    kvs_kernel<<<dim3(NCS, HH), 512, 0, stream>>>(kbhT, vbhT, gum, kvsp, ksp, ksump);
    reduce_kernel<<<392, 256, 0, stream>>>(kvsp, ksp, ksump, kvshT, kss, ksum);
    znum_kernel<<<dim3(469, HH), 256, 0, stream>>>(qbh, kvshT, kss, ksum, zout, nrm);
    outproj_kernel<<<1875, 256, 0, stream>>>(zout, Wo, bo, out);
    edge_bf16_kernel<<<60000, 256, 0, stream>>>(qbh, kbh, ei, nrm, out);
}

// Round 12
// 292.037 us; speedup vs baseline: 1.6459x; 1.1834x over previous
//
#include <hip/hip_runtime.h>
#include <hip/hip_bf16.h>

#define NN   30000
#define DIN  128
#define NHD  256      // H*D
#define HH   4
#define DD   64
#define MM   64
#define KK   6
#define EE   480000
#define ZOFF 1920000  // 30000*64
#define NCS   125
#define CHUNK 240
#define PITCH  30208   // padded bf16 elems per row of kbhT/vbhT
#define PITCH4 3776    // uint4 per row

typedef __attribute__((ext_vector_type(8))) short bf16x8;
typedef __attribute__((ext_vector_type(4))) float f32x4;

__device__ __forceinline__ unsigned f2key(float f) {
    unsigned u = __float_as_uint(f);
    return (u & 0x80000000u) ? ~u : (u | 0x80000000u);
}
__device__ __forceinline__ float key2f(unsigned k) {
    return __uint_as_float((k & 0x80000000u) ? (k ^ 0x80000000u) : ~k);
}
__device__ __forceinline__ unsigned short f2bf(float f) {   // RNE
    unsigned u = __float_as_uint(f);
    unsigned r = ((u >> 16) & 1u) + 0x7fffu;
    return (unsigned short)((u + r) >> 16);
}
__device__ __forceinline__ float bf2f(unsigned short u) {
    return __uint_as_float((unsigned)u << 16);
}

// ---------------------------------------------------------------- init
__global__ void init_kernel(unsigned* gmax) {
    if (threadIdx.x < HH) gmax[threadIdx.x] = 0u;
}

// ---------------------------------------------------------------- K0a: z -> bf16
__global__ __launch_bounds__(256) void zcast_kernel(
    const float* __restrict__ z, unsigned short* __restrict__ zh) {
    int idx = blockIdx.x * 256 + threadIdx.x;   // 960,000 float4 exactly
    float4 v = ((const float4*)z)[idx];
    ushort4 u;
    u.x = f2bf(v.x); u.y = f2bf(v.y); u.z = f2bf(v.z); u.w = f2bf(v.w);
    ((ushort4*)zh)[idx] = u;
}

// ---------------------------------------------------------------- K0b: W [128][256] -> WT bf16 [256][128]
__global__ __launch_bounds__(256) void wtransp_kernel(
    const float* __restrict__ Wq, const float* __restrict__ Wk,
    const float* __restrict__ Wv, unsigned short* __restrict__ WT) {
    __shared__ unsigned short tl[64][72];
    const int t = threadIdx.x;
    const int kt = blockIdx.x & 1, ct = blockIdx.x >> 1;
    const int wi = blockIdx.y;
    const float* W = (wi == 0) ? Wq : (wi == 1) ? Wk : Wv;
    const float4* W4 = (const float4*)W;
    #pragma unroll
    for (int it = 0; it < 4; ++it) {
        int idx = t + it * 256;       // 1024 = 64 k-rows x 16 float4
        int r = idx >> 4, c4 = idx & 15;
        float4 v = W4[(kt * 64 + r) * 64 + ct * 16 + c4];
        tl[c4 * 4 + 0][r] = f2bf(v.x);
        tl[c4 * 4 + 1][r] = f2bf(v.y);
        tl[c4 * 4 + 2][r] = f2bf(v.z);
        tl[c4 * 4 + 3][r] = f2bf(v.w);
    }
    __syncthreads();
    uint4* d4 = (uint4*)WT;
    #pragma unroll
    for (int it = 0; it < 2; ++it) {
        int idx = t + it * 256;       // 512 = 64 cols x 8 granules
        int m = idx >> 3, g = idx & 7;
        d4[((size_t)wi * 256 + ct * 64 + m) * 16 + kt * 8 + g] = *(uint4*)&tl[m][g * 8];
    }
}

// ---------------------------------------------------------------- K1: qkv via MFMA bf16
// grid (235, 3). A = WT rows (wcol), B = z rows (node); D[wcol][node].
__global__ __launch_bounds__(256) void qkv_mfma_kernel(
    const unsigned short* __restrict__ zh, const unsigned short* __restrict__ WT,
    const float* __restrict__ bq, const float* __restrict__ bk, const float* __restrict__ bv,
    float* __restrict__ qb, float* __restrict__ kb, float* __restrict__ vb) {
    __shared__ __align__(16) unsigned short zt[128 * 128];  // 32 KB
    __shared__ __align__(16) unsigned short wt[64 * 128];   // 16 KB
    const int t = threadIdx.x;
    const int n0 = blockIdx.x * 128;
    const int wi = blockIdx.y;
    const float sc = (wi == 2) ? 1.0f : 2.0f;
    const float* bias = (wi == 0) ? bq : (wi == 1) ? bk : bv;
    float* outp = (wi == 0) ? qb : (wi == 1) ? kb : vb;
    const uint4* zg = (const uint4*)zh;
    #pragma unroll
    for (int it = 0; it < 8; ++it) {
        int idx = t + it * 256;       // 2048 = 128 rows x 16 granules
        int row = idx >> 4, g = idx & 15;
        int n = n0 + row;
        uint4 v = make_uint4(0u, 0u, 0u, 0u);
        if (n < NN) v = zg[(size_t)n * 16 + g];
        *(uint4*)&zt[row * 128 + ((g ^ (row & 7)) * 8)] = v;
    }
    const uint4* wg = (const uint4*)WT + (size_t)wi * 4096;
    const int w = t >> 6, lane = t & 63, lrow = lane & 15, lk = lane >> 4;
    for (int cc = 0; cc < 4; ++cc) {
        __syncthreads();   // prev chunk's wt reads done (and zt staged for cc=0)
        #pragma unroll
        for (int it = 0; it < 4; ++it) {
            int idx = t + it * 256;   // 1024 = 64 rows x 16 granules
            int r = idx >> 4, g = idx & 15;
            *(uint4*)&wt[r * 128 + ((g ^ (r & 7)) * 8)] = wg[(cc * 64 + r) * 16 + g];
        }
        __syncthreads();
        f32x4 acc[4][2];
        #pragma unroll
        for (int mt = 0; mt < 4; ++mt) {
            acc[mt][0] = (f32x4){0.f, 0.f, 0.f, 0.f};
            acc[mt][1] = (f32x4){0.f, 0.f, 0.f, 0.f};
        }
        #pragma unroll
        for (int ks = 0; ks < 4; ++ks) {
            const int g0 = ks * 4 + lk;
            bf16x8 a[4], b[2];
            #pragma unroll
            for (int mt = 0; mt < 4; ++mt) {
                int r = mt * 16 + lrow;
                a[mt] = *(const bf16x8*)&wt[r * 128 + ((g0 ^ (r & 7)) * 8)];
            }
            #pragma unroll
            for (int nt = 0; nt < 2; ++nt) {
                int node = (w * 2 + nt) * 16 + lrow;
                b[nt] = *(const bf16x8*)&zt[node * 128 + ((g0 ^ (node & 7)) * 8)];
            }
            #pragma unroll
            for (int mt = 0; mt < 4; ++mt)
                #pragma unroll
                for (int nt = 0; nt < 2; ++nt)
                    acc[mt][nt] = __builtin_amdgcn_mfma_f32_16x16x32_bf16(
                        a[mt], b[nt], acc[mt][nt], 0, 0, 0);
        }
        #pragma unroll
        for (int mt = 0; mt < 4; ++mt) {
            int cbase = cc * 64 + mt * 16 + lk * 4;
            float4 bi = *(const float4*)&bias[cbase];
            #pragma unroll
            for (int nt = 0; nt < 2; ++nt) {
                int n = n0 + (w * 2 + nt) * 16 + lrow;
                if (n < NN) {
                    float4 o;
                    o.x = (acc[mt][nt][0] + bi.x) * sc;
                    o.y = (acc[mt][nt][1] + bi.y) * sc;
                    o.z = (acc[mt][nt][2] + bi.z) * sc;
                    o.w = (acc[mt][nt][3] + bi.w) * sc;
                    *(float4*)&outp[(size_t)n * NHD + cbase] = o;
                }
            }
        }
    }
}

// ---------------------------------------------------------------- K2: random features (GEMM form)
__global__ __launch_bounds__(256) void feat_kernel(
    float* __restrict__ qb, float* __restrict__ kb,
    const float* __restrict__ proj, unsigned* __restrict__ gmax,
    unsigned short* __restrict__ qbh) {
    __shared__ __align__(16) float pT[64][68];
    __shared__ __align__(16) float tT[64][68];
    __shared__ float diag_sh[64];
    __shared__ float wmax_sh[4];
    const int t = threadIdx.x;
    const int h = blockIdx.y;
    const int n0 = blockIdx.x * 64;
    const int tx = t & 15, ty = t >> 4;
    const float dn = 0.35355339059327373f;
    const float4* proj4 = (const float4*)proj;
    #pragma unroll
    for (int q = 0; q < 4; ++q) {
        int idx4 = t + q * 256;
        int m = idx4 >> 4, d4 = idx4 & 15;
        float4 v = proj4[m * 16 + d4];
        pT[d4 * 4 + 0][m] = v.x; pT[d4 * 4 + 1][m] = v.y;
        pT[d4 * 4 + 2][m] = v.z; pT[d4 * 4 + 3][m] = v.w;
    }
    #pragma unroll
    for (int pass = 0; pass < 2; ++pass) {
        float* buf = pass ? kb : qb;
        const float4* b4 = (const float4*)buf;
        __syncthreads();
        #pragma unroll
        for (int q = 0; q < 4; ++q) {
            int idx4 = t + q * 256;
            int n = idx4 >> 4, d4 = idx4 & 15;
            float4 v = make_float4(0.f, 0.f, 0.f, 0.f);
            if (n0 + n < NN) v = b4[(n0 + n) * 64 + h * 16 + d4];
            tT[d4 * 4 + 0][n] = v.x * dn; tT[d4 * 4 + 1][n] = v.y * dn;
            tT[d4 * 4 + 2][n] = v.z * dn; tT[d4 * 4 + 3][n] = v.w * dn;
        }
        __syncthreads();
        if (t < 64) {
            float s = 0.f;
            #pragma unroll 8
            for (int d = 0; d < 64; ++d) { float v = tT[d][t]; s += v * v; }
            diag_sh[t] = 0.5f * s;
        }
        __syncthreads();
        float acc[4][4];
        #pragma unroll
        for (int i = 0; i < 4; ++i)
            #pragma unroll
            for (int j = 0; j < 4; ++j) acc[i][j] = 0.f;
        #pragma unroll 8
        for (int d = 0; d < 64; ++d) {
            float4 a = *(const float4*)&tT[d][ty * 4];
            float4 b = *(const float4*)&pT[d][tx * 4];
            float a_[4] = {a.x, a.y, a.z, a.w};
            float b_[4] = {b.x, b.y, b.z, b.w};
            #pragma unroll
            for (int i = 0; i < 4; ++i)
                #pragma unroll
                for (int j = 0; j < 4; ++j) acc[i][j] += a_[i] * b_[j];
        }
        if (pass == 0) {
            #pragma unroll
            for (int i = 0; i < 4; ++i) {
                int n = n0 + ty * 4 + i;
                float mx = fmaxf(fmaxf(acc[i][0], acc[i][1]), fmaxf(acc[i][2], acc[i][3]));
                mx = fmaxf(mx, __shfl_xor(mx, 1, 64));
                mx = fmaxf(mx, __shfl_xor(mx, 2, 64));
                mx = fmaxf(mx, __shfl_xor(mx, 4, 64));
                mx = fmaxf(mx, __shfl_xor(mx, 8, 64));
                if (n < NN) {
                    float dg = diag_sh[ty * 4 + i] + mx;
                    ushort4 u;
                    u.x = f2bf(0.125f * (__expf(acc[i][0] - dg) + 1e-6f));
                    u.y = f2bf(0.125f * (__expf(acc[i][1] - dg) + 1e-6f));
                    u.z = f2bf(0.125f * (__expf(acc[i][2] - dg) + 1e-6f));
                    u.w = f2bf(0.125f * (__expf(acc[i][3] - dg) + 1e-6f));
                    *(ushort4*)&qbh[n * NHD + h * DD + tx * 4] = u;
                }
            }
        } else {
            float km = -3.4e38f;
            #pragma unroll
            for (int i = 0; i < 4; ++i) {
                int n = n0 + ty * 4 + i;
                if (n < NN) {
                    float dg = diag_sh[ty * 4 + i];
                    float4 o;
                    o.x = acc[i][0] - dg; o.y = acc[i][1] - dg;
                    o.z = acc[i][2] - dg; o.w = acc[i][3] - dg;
                    *(float4*)&kb[n * NHD + h * DD + tx * 4] = o;
                    km = fmaxf(km, fmaxf(fmaxf(acc[i][0], acc[i][1]),
                                         fmaxf(acc[i][2], acc[i][3])));
                }
            }
            #pragma unroll
            for (int off = 1; off < 64; off <<= 1) km = fmaxf(km, __shfl_xor(km, off, 64));
            if ((t & 63) == 0) wmax_sh[t >> 6] = km;
            __syncthreads();
            if (t == 0) {
                float m2 = fmaxf(fmaxf(wmax_sh[0], wmax_sh[1]), fmaxf(wmax_sh[2], wmax_sh[3]));
                atomicMax(&gmax[h], f2key(m2));
            }
        }
    }
}

// ---------------------------------------------------------------- K3: kp finalize (float4 + bf16 mirror)
__global__ void kfin_kernel(float* __restrict__ kb, const unsigned* __restrict__ gmax,
                            unsigned short* __restrict__ kbh) {
    int idx = (blockIdx.x * 256 + threadIdx.x) * 4;
    int h = (idx >> 6) & 3;
    float mx = key2f(gmax[h]);
    float4 v = *(float4*)&kb[idx];
    v.x = 0.125f * (__expf(v.x - mx) + 1e-6f);
    v.y = 0.125f * (__expf(v.y - mx) + 1e-6f);
    v.z = 0.125f * (__expf(v.z - mx) + 1e-6f);
    v.w = 0.125f * (__expf(v.w - mx) + 1e-6f);
    *(float4*)&kb[idx] = v;
    ushort4 u;
    u.x = f2bf(v.x); u.y = f2bf(v.y); u.z = f2bf(v.z); u.w = f2bf(v.w);
    *(ushort4*)&kbh[idx] = u;
}

// ---------------------------------------------------------------- K3b: transpose f32 [n][h*64+c] -> bf16 [h*64+c][n]
__global__ __launch_bounds__(256) void transp_kernel(
    const float* __restrict__ src, unsigned short* __restrict__ dst) {
    __shared__ unsigned short tl[64][72];
    const int t = threadIdx.x;
    const int nt = blockIdx.x * 64;
    const int h = blockIdx.y;
    const float4* s4 = (const float4*)src;
    #pragma unroll
    for (int it = 0; it < 4; ++it) {
        int idx = t + it * 256;
        int c4 = idx & 15, n = idx >> 4;
        float4 v = make_float4(0.f, 0.f, 0.f, 0.f);
        if (nt + n < NN) v = s4[(size_t)(nt + n) * 64 + h * 16 + c4];
        tl[c4 * 4 + 0][n] = f2bf(v.x);
        tl[c4 * 4 + 1][n] = f2bf(v.y);
        tl[c4 * 4 + 2][n] = f2bf(v.z);
        tl[c4 * 4 + 3][n] = f2bf(v.w);
    }
    __syncthreads();
    uint4* d4 = (uint4*)dst;
    #pragma unroll
    for (int it = 0; it < 2; ++it) {
        int idx = t + it * 256;
        int g = idx & 7, m = idx >> 3;
        d4[(size_t)(h * 64 + m) * PITCH4 + (nt >> 3) + g] = *(uint4*)&tl[m][g * 8];
    }
}

// ---------------------------------------------------------------- K4: kvs via MFMA bf16
__global__ __launch_bounds__(512) void kvs_kernel(
    const unsigned short* __restrict__ kbhT, const unsigned short* __restrict__ vbhT,
    const float* __restrict__ gum,
    unsigned short* __restrict__ kvsp, float* __restrict__ ksp, float* __restrict__ ksump) {
    __shared__ __align__(16) unsigned short kpa[64 * 64];
    __shared__ __align__(16) unsigned short va [64 * 64];
    __shared__ __align__(16) unsigned short kpwa[64 * 64];
    __shared__ float w_sh[KK][256];
    const int c = blockIdx.x, h = blockIdx.y;
    const int t = threadIdx.x;
    const int n0 = c * CHUNK;
    const int n1 = n0 + CHUNK;
    for (int i = t; i < 256; i += 512) {
        int n = n0 + i;
        bool ok = (i < CHUNK);
        #pragma unroll
        for (int k = 0; k < KK; ++k)
            w_sh[k][i] = ok ? __expf(gum[n * 24 + h * KK + k] * 4.0f) : 0.f;
    }
    const int m_ = t >> 3, g_ = t & 7;
    const int w = t >> 6, lane = t & 63, lrow = lane & 15, lk = lane >> 4;
    const int ds = w & 3, mh = w >> 2;
    const int arow = ds * 16 + lrow;
    f32x4 acc[KK][2];
    #pragma unroll
    for (int k = 0; k < KK; ++k) {
        acc[k][0] = (f32x4){0.f, 0.f, 0.f, 0.f};
        acc[k][1] = (f32x4){0.f, 0.f, 0.f, 0.f};
    }
    float ks_acc[KK] = {0.f, 0.f, 0.f, 0.f, 0.f, 0.f};
    float ksum_acc = 0.f;
    const uint4* kT4 = (const uint4*)kbhT;
    const uint4* vT4 = (const uint4*)vbhT;
    #pragma unroll
    for (int s = 0; s < 4; ++s) {
        const int nb = n0 + s * 64;
        __syncthreads();
        uint4 kvv = kT4[(size_t)(h * 64 + m_) * PITCH4 + (nb >> 3) + g_];
        uint4 vvv = vT4[(size_t)(h * 64 + m_) * PITCH4 + (nb >> 3) + g_];
        const int slot = g_ ^ (m_ & 7);
        *(uint4*)&kpa[m_ * 64 + slot * 8] = kvv;
        *(uint4*)&va [m_ * 64 + slot * 8] = vvv;
        float kf[8];
        {
            const unsigned short* ke = (const unsigned short*)&kvv;
            float sl = 0.f;
            int nbase = nb + g_ * 8;
            #pragma unroll
            for (int e = 0; e < 8; ++e) {
                kf[e] = bf2f(ke[e]);
                if (nbase + e < n1) sl += kf[e];
            }
            sl += __shfl_xor(sl, 1, 64);
            sl += __shfl_xor(sl, 2, 64);
            sl += __shfl_xor(sl, 4, 64);
            if (g_ == 0) ksum_acc += sl;
        }
        __syncthreads();
        bf16x8 a0 = *(const bf16x8*)&va[arow * 64 + ((lk ^ (arow & 7)) * 8)];
        bf16x8 a1 = *(const bf16x8*)&va[arow * 64 + (((lk + 4) ^ (arow & 7)) * 8)];
        const int bw = s * 64;
        const int gg = g_ ^ (m_ & 7);
        #pragma unroll
        for (int k = 0; k < KK; ++k) {
            {
                unsigned short ov[8];
                float sl = 0.f;
                #pragma unroll
                for (int e = 0; e < 8; ++e) {
                    float p = kf[e] * w_sh[k][bw + gg * 8 + e];
                    sl += p;
                    ov[e] = f2bf(p);
                }
                *(uint4*)&kpwa[m_ * 64 + g_ * 8] = *(uint4*)ov;
                sl += __shfl_xor(sl, 1, 64);
                sl += __shfl_xor(sl, 2, 64);
                sl += __shfl_xor(sl, 4, 64);
                if (g_ == 0) ks_acc[k] += sl;
            }
            __syncthreads();
            #pragma unroll
            for (int mt = 0; mt < 2; ++mt) {
                int m = (mh * 2 + mt) * 16 + lrow;
                bf16x8 b0 = *(const bf16x8*)&kpwa[m * 64 + ((lk ^ (m & 7)) * 8)];
                bf16x8 b1 = *(const bf16x8*)&kpwa[m * 64 + (((lk + 4) ^ (m & 7)) * 8)];
                acc[k][mt] = __builtin_amdgcn_mfma_f32_16x16x32_bf16(a0, b0, acc[k][mt], 0, 0, 0);
                acc[k][mt] = __builtin_amdgcn_mfma_f32_16x16x32_bf16(a1, b1, acc[k][mt], 0, 0, 0);
            }
            __syncthreads();
        }
    }
    const size_t cb = (size_t)(c * HH + h) * KK;
    #pragma unroll
    for (int k = 0; k < KK; ++k)
        #pragma unroll
        for (int mt = 0; mt < 2; ++mt) {
            int m = (mh * 2 + mt) * 16 + lrow;
            #pragma unroll
            for (int r = 0; r < 4; ++r) {
                int d = ds * 16 + lk * 4 + r;
                kvsp[(cb + k) * 4096 + d * 64 + m] = f2bf(acc[k][mt][r]);
            }
        }
    if (g_ == 0) {
        #pragma unroll
        for (int k = 0; k < KK; ++k)
            ksp[(cb + k) * 64 + m_] = ks_acc[k];
        ksump[(size_t)(c * HH + h) * 64 + m_] = ksum_acc;
    }
}

// ---------------------------------------------------------------- K5: reduce bf16 partials -> kvshT, f32 ks/ksum
__global__ void reduce_kernel(const unsigned short* __restrict__ kvsp,
                              const float* __restrict__ ksp, const float* __restrict__ ksump,
                              unsigned short* __restrict__ kvshT, float* __restrict__ kss,
                              float* __restrict__ ksum) {
    int idx = blockIdx.x * 256 + threadIdx.x;
    if (idx < 98304) {
        float s = 0.f;
        for (int c = 0; c < NCS; ++c) s += bf2f(kvsp[c * 98304 + idx]);
        kvshT[idx] = f2bf(s);
    } else if (idx < 98304 + 1536) {
        int o = idx - 98304;
        float s = 0.f;
        for (int c = 0; c < NCS; ++c) s += ksp[c * 1536 + o];
        kss[o] = s;
    } else if (idx < 98304 + 1536 + 256) {
        int o = idx - 98304 - 1536;
        float s = 0.f;
        for (int c = 0; c < NCS; ++c) s += ksump[c * 256 + o];
        ksum[o] = s;
    }
}

// ---------------------------------------------------------------- K6: znum via MFMA bf16 (proven)
__global__ __launch_bounds__(256) void znum_kernel(
    const unsigned short* __restrict__ qbh, const unsigned short* __restrict__ kvshT,
    const float* __restrict__ kss, const float* __restrict__ ksum,
    float* __restrict__ zout, float* __restrict__ nrm) {
    __shared__ __align__(16) unsigned short qpa[64 * 64];
    __shared__ __align__(16) unsigned short bt[6 * 64 * 64];
    __shared__ float ks_sh[384];
    __shared__ float ksum_sh[64];
    __shared__ float zdi[64 * 6];
    const int t = threadIdx.x;
    const int h = blockIdx.y;
    const int n0 = blockIdx.x * 64;
    const uint4* qg = (const uint4*)qbh;
    #pragma unroll
    for (int q = 0; q < 2; ++q) {
        int idx = t + q * 256;
        int row = idx >> 3, c8 = idx & 7;
        int n = n0 + row;
        uint4 v = make_uint4(0u, 0u, 0u, 0u);
        if (n < NN) v = qg[n * 32 + h * 8 + c8];
        *(uint4*)&qpa[row * 64 + ((c8 ^ (row & 7)) * 8)] = v;
    }
    const uint4* bg = (const uint4*)kvshT;
    #pragma unroll
    for (int q = 0; q < 12; ++q) {
        int idx = t + q * 256;
        int kd = idx >> 3, c8 = idx & 7;
        *(uint4*)&bt[kd * 64 + ((c8 ^ (kd & 7)) * 8)] = bg[h * 3072 + idx];
    }
    for (int i = t; i < 384; i += 256) ks_sh[i] = kss[h * 384 + i];
    if (t < 64) ksum_sh[t] = ksum[h * 64 + t];
    __syncthreads();
    for (int idx = t; idx < 512; idx += 256) {
        if (idx < 384) {
            int node = idx / 6, k = idx - node * 6;
            int swz = (node & 7) << 3;
            float s = 0.f;
            for (int m = 0; m < 64; ++m)
                s += bf2f(qpa[node * 64 + (m ^ swz)]) * ks_sh[k * 64 + m];
            zdi[node * 6 + k] = 1.0f / s;
        } else if (idx < 448) {
            int node = idx - 384;
            int swz = (node & 7) << 3;
            float s = 0.f;
            for (int m = 0; m < 64; ++m)
                s += bf2f(qpa[node * 64 + (m ^ swz)]) * ksum_sh[m];
            int n = n0 + node;
            if (n < NN) nrm[n * HH + h] = s;
        }
    }
    __syncthreads();
    const int w = t >> 6, lane = t & 63;
    const int lrow = lane & 15, lk = lane >> 4;
    const int arow = w * 16 + lrow;
    const int aswz = (arow & 7) << 3;
    bf16x8 a0 = *(const bf16x8*)&qpa[arow * 64 + ((lk * 8) ^ aswz)];
    bf16x8 a1 = *(const bf16x8*)&qpa[arow * 64 + ((lk * 8 + 32) ^ aswz)];
    const float inv6 = 1.0f / 6.0f;
    #pragma unroll
    for (int dt = 0; dt < 4; ++dt) {
        f32x4 outv = {0.f, 0.f, 0.f, 0.f};
        #pragma unroll
        for (int k = 0; k < KK; ++k) {
            int kd = k * 64 + dt * 16 + lrow;
            int sw = (kd & 7) << 3;
            bf16x8 b0 = *(const bf16x8*)&bt[kd * 64 + ((lk * 8) ^ sw)];
            bf16x8 b1 = *(const bf16x8*)&bt[kd * 64 + ((lk * 8 + 32) ^ sw)];
            f32x4 acc = {0.f, 0.f, 0.f, 0.f};
            acc = __builtin_amdgcn_mfma_f32_16x16x32_bf16(a0, b0, acc, 0, 0, 0);
            acc = __builtin_amdgcn_mfma_f32_16x16x32_bf16(a1, b1, acc, 0, 0, 0);
            #pragma unroll
            for (int r = 0; r < 4; ++r)
                outv[r] += zdi[(w * 16 + lk * 4 + r) * 6 + k] * acc[r];
        }
        #pragma unroll
        for (int r = 0; r < 4; ++r) {
            int n = n0 + w * 16 + lk * 4 + r;
            if (n < NN) zout[(size_t)n * NHD + h * DD + dt * 16 + lrow] = outv[r] * inv6;
        }
    }
}

// ---------------------------------------------------------------- K7: output projection (f32 out)
__global__ __launch_bounds__(256) void outproj_kernel(
    const float* __restrict__ zout, const float* __restrict__ Wo,
    const float* __restrict__ bo, float* __restrict__ out) {
    __shared__ float zsh[16][NHD];
    const int t = threadIdx.x;
    const int n0 = blockIdx.x * 16;
    #pragma unroll
    for (int q = 0; q < 16; ++q) {
        int idx = t + q * 256;
        int nn2 = idx >> 8, r = idx & 255;
        zsh[nn2][r] = zout[(n0 + nn2) * NHD + r];
    }
    __syncthreads();
    const int c = t & 63, g = t >> 6;
    float acc[4];
    #pragma unroll
    for (int i = 0; i < 4; ++i) acc[i] = bo[c];
    for (int r = 0; r < 256; ++r) {
        float w = Wo[r * 64 + c];
        #pragma unroll
        for (int i = 0; i < 4; ++i) acc[i] += zsh[g + 4 * i][r] * w;
    }
    #pragma unroll
    for (int i = 0; i < 4; ++i)
        out[(n0 + g + 4 * i) * 64 + c] = acc[i];
}

// ---------------------------------------------------------------- K8: edges, bf16 gather
__global__ __launch_bounds__(256) void edge_bf16_kernel(
    const unsigned short* __restrict__ qbh, const unsigned short* __restrict__ kbh,
    const int* __restrict__ ei, const float* __restrict__ nrm,
    float* __restrict__ out) {
    const int t = threadIdx.x;
    const int lane5 = t & 31;
    const int e = blockIdx.x * 8 + (t >> 5);
    const int s = ei[e], d = ei[EE + e];
    const uint4* q4 = (const uint4*)qbh;
    const uint4* k4 = (const uint4*)kbh;
    uint4 qv = q4[d * 32 + lane5];
    uint4 kv = k4[s * 32 + lane5];
    const unsigned short* qs = (const unsigned short*)&qv;
    const unsigned short* ks = (const unsigned short*)&kv;
    float p = 0.f;
    #pragma unroll
    for (int i = 0; i < 8; ++i) p += bf2f(qs[i]) * bf2f(ks[i]);
    p += __shfl_xor(p, 1, 64);
    p += __shfl_xor(p, 2, 64);
    p += __shfl_xor(p, 4, 64);
    if ((lane5 & 7) == 0) {
        int h = lane5 >> 3;
        out[ZOFF + e * 4 + h] = p / nrm[d * HH + h];
    }
}

// ---------------------------------------------------------------- launch
extern "C" void kernel_launch(void* const* d_in, const int* in_sizes, int n_in,
                              void* d_out, int out_size, void* d_ws, size_t ws_size,
                              hipStream_t stream) {
    (void)in_sizes; (void)n_in; (void)out_size;
    const float* z  = (const float*)d_in[0];
    const float* Wq = (const float*)d_in[1];
    const float* bq = (const float*)d_in[2];
    const float* Wk = (const float*)d_in[3];
    const float* bk = (const float*)d_in[4];
    const float* Wv = (const float*)d_in[5];
    const float* bv = (const float*)d_in[6];
    const float* Wo = (const float*)d_in[7];
    const float* bo = (const float*)d_in[8];
    const float* proj = (const float*)d_in[9];
    const float* gum  = (const float*)d_in[10];
    const int*   ei   = (const int*)d_in[11];
    float* out = (float*)d_out;
    float* ws = (float*)d_ws;

    if (ws_size / 4 < (size_t)38673348) return;

    float* qb    = ws;                  // raw q; region reused for kvs partials after feat
    float* kb    = ws + 7680000;
    float* vb    = ws + 15360000;       // reused as zout
    float* zout  = vb;
    unsigned short* kvshT = (unsigned short*)(ws + 23040000);  // 98,304 bf16
    float* kss   = ws + 23138304;       // 1,536
    float* ksum  = ws + 23139840;       // 256
    float* nrm   = ws + 23140096;       // 120,000
    unsigned* gmax = (unsigned*)(ws + 23260096);  // 4
    unsigned short* qbh = (unsigned short*)(ws + 23260100);    // 7.68M bf16
    unsigned short* kbh = (unsigned short*)(ws + 27100100);    // 7.68M bf16
    unsigned short* kbhT = (unsigned short*)(ws + 30940100);   // 256*30208 bf16
    unsigned short* vbhT = (unsigned short*)(ws + 34806724);   // 256*30208 bf16
    // pre-qkv scratch aliases the not-yet-live qbh region:
    unsigned short* zh = (unsigned short*)(ws + 23260100);     // 3.84M bf16
    unsigned short* WT = (unsigned short*)(ws + 25180100);     // 98,304 bf16
    // kvs partials alias qb (dead after feat):
    float* ksp   = ws;                              // 125*1536
    float* ksump = ws + 192000;                     // 125*256
    unsigned short* kvsp = (unsigned short*)(ws + 224000);  // 125*98304 bf16

    init_kernel<<<1, 64, 0, stream>>>(gmax);
    zcast_kernel<<<3750, 256, 0, stream>>>(z, zh);
    wtransp_kernel<<<dim3(8, 3), 256, 0, stream>>>(Wq, Wk, Wv, WT);
    qkv_mfma_kernel<<<dim3(235, 3), 256, 0, stream>>>(zh, WT, bq, bk, bv, qb, kb, vb);
    feat_kernel<<<dim3(469, HH), 256, 0, stream>>>(qb, kb, proj, gmax, qbh);
    kfin_kernel<<<7500, 256, 0, stream>>>(kb, gmax, kbh);
    transp_kernel<<<dim3(472, HH), 256, 0, stream>>>(kb, kbhT);
    transp_kernel<<<dim3(472, HH), 256, 0, stream>>>(vb, vbhT);
    kvs_kernel<<<dim3(NCS, HH), 512, 0, stream>>>(kbhT, vbhT, gum, kvsp, ksp, ksump);
    reduce_kernel<<<392, 256, 0, stream>>>(kvsp, ksp, ksump, kvshT, kss, ksum);
    znum_kernel<<<dim3(469, HH), 256, 0, stream>>>(qbh, kvshT, kss, ksum, zout, nrm);
    outproj_kernel<<<1875, 256, 0, stream>>>(zout, Wo, bo, out);
    edge_bf16_kernel<<<60000, 256, 0, stream>>>(qbh, kbh, ei, nrm, out);
}

// Round 13
// 276.484 us; speedup vs baseline: 1.7385x; 1.0563x over previous
//
#include <hip/hip_runtime.h>
#include <hip/hip_bf16.h>

#define NN   30000
#define DIN  128
#define NHD  256      // H*D
#define HH   4
#define DD   64
#define MM   64
#define KK   6
#define EE   480000
#define ZOFF 1920000  // 30000*64
#define NCS   125
#define CHUNK 240
#define PITCH  30208   // padded bf16 elems per row of kbhT/vbhT
#define PITCH4 3776    // uint4 per row

typedef __attribute__((ext_vector_type(8))) short bf16x8;
typedef __attribute__((ext_vector_type(4))) float f32x4;

__device__ __forceinline__ unsigned f2key(float f) {
    unsigned u = __float_as_uint(f);
    return (u & 0x80000000u) ? ~u : (u | 0x80000000u);
}
__device__ __forceinline__ float key2f(unsigned k) {
    return __uint_as_float((k & 0x80000000u) ? (k ^ 0x80000000u) : ~k);
}
__device__ __forceinline__ unsigned short f2bf(float f) {   // RNE
    unsigned u = __float_as_uint(f);
    unsigned r = ((u >> 16) & 1u) + 0x7fffu;
    return (unsigned short)((u + r) >> 16);
}
__device__ __forceinline__ float bf2f(unsigned short u) {
    return __uint_as_float((unsigned)u << 16);
}

// ---------------------------------------------------------------- init
__global__ void init_kernel(unsigned* gmax) {
    if (threadIdx.x < HH) gmax[threadIdx.x] = 0u;
}

// ---------------------------------------------------------------- K0a: z -> bf16
__global__ __launch_bounds__(256) void zcast_kernel(
    const float* __restrict__ z, unsigned short* __restrict__ zh) {
    int idx = blockIdx.x * 256 + threadIdx.x;   // 960,000 float4 exactly
    float4 v = ((const float4*)z)[idx];
    ushort4 u;
    u.x = f2bf(v.x); u.y = f2bf(v.y); u.z = f2bf(v.z); u.w = f2bf(v.w);
    ((ushort4*)zh)[idx] = u;
}

// ---------------------------------------------------------------- K0b: W [128][256] -> WT bf16 [256][128]
__global__ __launch_bounds__(256) void wtransp_kernel(
    const float* __restrict__ Wq, const float* __restrict__ Wk,
    const float* __restrict__ Wv, unsigned short* __restrict__ WT) {
    __shared__ unsigned short tl[64][72];
    const int t = threadIdx.x;
    const int kt = blockIdx.x & 1, ct = blockIdx.x >> 1;
    const int wi = blockIdx.y;
    const float* W = (wi == 0) ? Wq : (wi == 1) ? Wk : Wv;
    const float4* W4 = (const float4*)W;
    #pragma unroll
    for (int it = 0; it < 4; ++it) {
        int idx = t + it * 256;       // 1024 = 64 k-rows x 16 float4
        int r = idx >> 4, c4 = idx & 15;
        float4 v = W4[(kt * 64 + r) * 64 + ct * 16 + c4];
        tl[c4 * 4 + 0][r] = f2bf(v.x);
        tl[c4 * 4 + 1][r] = f2bf(v.y);
        tl[c4 * 4 + 2][r] = f2bf(v.z);
        tl[c4 * 4 + 3][r] = f2bf(v.w);
    }
    __syncthreads();
    uint4* d4 = (uint4*)WT;
    #pragma unroll
    for (int it = 0; it < 2; ++it) {
        int idx = t + it * 256;       // 512 = 64 cols x 8 granules
        int m = idx >> 3, g = idx & 7;
        d4[((size_t)wi * 256 + ct * 64 + m) * 16 + kt * 8 + g] = *(uint4*)&tl[m][g * 8];
    }
}

// ---------------------------------------------------------------- K1: qkv via MFMA bf16, bf16 outputs
__global__ __launch_bounds__(256) void qkv_mfma_kernel(
    const unsigned short* __restrict__ zh, const unsigned short* __restrict__ WT,
    const float* __restrict__ bq, const float* __restrict__ bk, const float* __restrict__ bv,
    unsigned short* __restrict__ qh, unsigned short* __restrict__ kh,
    unsigned short* __restrict__ vh) {
    __shared__ __align__(16) unsigned short zt[128 * 128];  // 32 KB
    __shared__ __align__(16) unsigned short wt[64 * 128];   // 16 KB
    const int t = threadIdx.x;
    const int n0 = blockIdx.x * 128;
    const int wi = blockIdx.y;
    const float sc = (wi == 2) ? 1.0f : 2.0f;
    const float* bias = (wi == 0) ? bq : (wi == 1) ? bk : bv;
    unsigned short* outp = (wi == 0) ? qh : (wi == 1) ? kh : vh;
    const uint4* zg = (const uint4*)zh;
    #pragma unroll
    for (int it = 0; it < 8; ++it) {
        int idx = t + it * 256;       // 2048 = 128 rows x 16 granules
        int row = idx >> 4, g = idx & 15;
        int n = n0 + row;
        uint4 v = make_uint4(0u, 0u, 0u, 0u);
        if (n < NN) v = zg[(size_t)n * 16 + g];
        *(uint4*)&zt[row * 128 + ((g ^ (row & 7)) * 8)] = v;
    }
    const uint4* wg = (const uint4*)WT + (size_t)wi * 4096;
    const int w = t >> 6, lane = t & 63, lrow = lane & 15, lk = lane >> 4;
    for (int cc = 0; cc < 4; ++cc) {
        __syncthreads();
        #pragma unroll
        for (int it = 0; it < 4; ++it) {
            int idx = t + it * 256;   // 1024 = 64 rows x 16 granules
            int r = idx >> 4, g = idx & 15;
            *(uint4*)&wt[r * 128 + ((g ^ (r & 7)) * 8)] = wg[(cc * 64 + r) * 16 + g];
        }
        __syncthreads();
        f32x4 acc[4][2];
        #pragma unroll
        for (int mt = 0; mt < 4; ++mt) {
            acc[mt][0] = (f32x4){0.f, 0.f, 0.f, 0.f};
            acc[mt][1] = (f32x4){0.f, 0.f, 0.f, 0.f};
        }
        #pragma unroll
        for (int ks = 0; ks < 4; ++ks) {
            const int g0 = ks * 4 + lk;
            bf16x8 a[4], b[2];
            #pragma unroll
            for (int mt = 0; mt < 4; ++mt) {
                int r = mt * 16 + lrow;
                a[mt] = *(const bf16x8*)&wt[r * 128 + ((g0 ^ (r & 7)) * 8)];
            }
            #pragma unroll
            for (int nt = 0; nt < 2; ++nt) {
                int node = (w * 2 + nt) * 16 + lrow;
                b[nt] = *(const bf16x8*)&zt[node * 128 + ((g0 ^ (node & 7)) * 8)];
            }
            #pragma unroll
            for (int mt = 0; mt < 4; ++mt)
                #pragma unroll
                for (int nt = 0; nt < 2; ++nt)
                    acc[mt][nt] = __builtin_amdgcn_mfma_f32_16x16x32_bf16(
                        a[mt], b[nt], acc[mt][nt], 0, 0, 0);
        }
        #pragma unroll
        for (int mt = 0; mt < 4; ++mt) {
            int cbase = cc * 64 + mt * 16 + lk * 4;
            float4 bi = *(const float4*)&bias[cbase];
            #pragma unroll
            for (int nt = 0; nt < 2; ++nt) {
                int n = n0 + (w * 2 + nt) * 16 + lrow;
                if (n < NN) {
                    ushort4 u;
                    u.x = f2bf((acc[mt][nt][0] + bi.x) * sc);
                    u.y = f2bf((acc[mt][nt][1] + bi.y) * sc);
                    u.z = f2bf((acc[mt][nt][2] + bi.z) * sc);
                    u.w = f2bf((acc[mt][nt][3] + bi.w) * sc);
                    *(ushort4*)&outp[(size_t)n * NHD + cbase] = u;
                }
            }
        }
    }
}

// ---------------------------------------------------------------- K2: random features (bf16 in, qp in-place)
__global__ __launch_bounds__(256) void feat_kernel(
    const unsigned short* __restrict__ qh, const unsigned short* __restrict__ kh,
    float* __restrict__ kb,
    const float* __restrict__ proj, unsigned* __restrict__ gmax,
    unsigned short* __restrict__ qbh) {
    __shared__ __align__(16) float pT[64][68];
    __shared__ __align__(16) float tT[64][68];
    __shared__ float diag_sh[64];
    __shared__ float wmax_sh[4];
    const int t = threadIdx.x;
    const int h = blockIdx.y;
    const int n0 = blockIdx.x * 64;
    const int tx = t & 15, ty = t >> 4;
    const float dn = 0.35355339059327373f;
    const float4* proj4 = (const float4*)proj;
    #pragma unroll
    for (int q = 0; q < 4; ++q) {
        int idx4 = t + q * 256;
        int m = idx4 >> 4, d4 = idx4 & 15;
        float4 v = proj4[m * 16 + d4];
        pT[d4 * 4 + 0][m] = v.x; pT[d4 * 4 + 1][m] = v.y;
        pT[d4 * 4 + 2][m] = v.z; pT[d4 * 4 + 3][m] = v.w;
    }
    #pragma unroll
    for (int pass = 0; pass < 2; ++pass) {
        const uint4* b4 = (const uint4*)(pass ? kh : qh);
        __syncthreads();
        #pragma unroll
        for (int q = 0; q < 2; ++q) {
            int idx = t + q * 256;       // 512 = 64 rows x 8 granules
            int n = idx >> 3, g = idx & 7;
            uint4 v = make_uint4(0u, 0u, 0u, 0u);
            if (n0 + n < NN) v = b4[(size_t)(n0 + n) * 32 + h * 8 + g];
            const unsigned short* e = (const unsigned short*)&v;
            #pragma unroll
            for (int j = 0; j < 8; ++j) tT[g * 8 + j][n] = bf2f(e[j]) * dn;
        }
        __syncthreads();
        if (t < 64) {
            float s = 0.f;
            #pragma unroll 8
            for (int d = 0; d < 64; ++d) { float v = tT[d][t]; s += v * v; }
            diag_sh[t] = 0.5f * s;
        }
        __syncthreads();
        float acc[4][4];
        #pragma unroll
        for (int i = 0; i < 4; ++i)
            #pragma unroll
            for (int j = 0; j < 4; ++j) acc[i][j] = 0.f;
        #pragma unroll 8
        for (int d = 0; d < 64; ++d) {
            float4 a = *(const float4*)&tT[d][ty * 4];
            float4 b = *(const float4*)&pT[d][tx * 4];
            float a_[4] = {a.x, a.y, a.z, a.w};
            float b_[4] = {b.x, b.y, b.z, b.w};
            #pragma unroll
            for (int i = 0; i < 4; ++i)
                #pragma unroll
                for (int j = 0; j < 4; ++j) acc[i][j] += a_[i] * b_[j];
        }
        if (pass == 0) {
            #pragma unroll
            for (int i = 0; i < 4; ++i) {
                int n = n0 + ty * 4 + i;
                float mx = fmaxf(fmaxf(acc[i][0], acc[i][1]), fmaxf(acc[i][2], acc[i][3]));
                mx = fmaxf(mx, __shfl_xor(mx, 1, 64));
                mx = fmaxf(mx, __shfl_xor(mx, 2, 64));
                mx = fmaxf(mx, __shfl_xor(mx, 4, 64));
                mx = fmaxf(mx, __shfl_xor(mx, 8, 64));
                if (n < NN) {
                    float dg = diag_sh[ty * 4 + i] + mx;
                    ushort4 u;
                    u.x = f2bf(0.125f * (__expf(acc[i][0] - dg) + 1e-6f));
                    u.y = f2bf(0.125f * (__expf(acc[i][1] - dg) + 1e-6f));
                    u.z = f2bf(0.125f * (__expf(acc[i][2] - dg) + 1e-6f));
                    u.w = f2bf(0.125f * (__expf(acc[i][3] - dg) + 1e-6f));
                    *(ushort4*)&qbh[n * NHD + h * DD + tx * 4] = u;
                }
            }
        } else {
            float km = -3.4e38f;
            #pragma unroll
            for (int i = 0; i < 4; ++i) {
                int n = n0 + ty * 4 + i;
                if (n < NN) {
                    float dg = diag_sh[ty * 4 + i];
                    float4 o;
                    o.x = acc[i][0] - dg; o.y = acc[i][1] - dg;
                    o.z = acc[i][2] - dg; o.w = acc[i][3] - dg;
                    *(float4*)&kb[n * NHD + h * DD + tx * 4] = o;
                    km = fmaxf(km, fmaxf(fmaxf(acc[i][0], acc[i][1]),
                                         fmaxf(acc[i][2], acc[i][3])));
                }
            }
            #pragma unroll
            for (int off = 1; off < 64; off <<= 1) km = fmaxf(km, __shfl_xor(km, off, 64));
            if ((t & 63) == 0) wmax_sh[t >> 6] = km;
            __syncthreads();
            if (t == 0) {
                float m2 = fmaxf(fmaxf(wmax_sh[0], wmax_sh[1]), fmaxf(wmax_sh[2], wmax_sh[3]));
                atomicMax(&gmax[h], f2key(m2));
            }
        }
    }
}

// ---------------------------------------------------------------- K3: fused kp finalize + transpose
// grid (472, 4). Reads kb f32 (dd-diag), writes kbh [n][256] bf16 AND kbhT [h*64+c][n] bf16.
__global__ __launch_bounds__(256) void kfin_tr_kernel(
    const float* __restrict__ kb, const unsigned* __restrict__ gmax,
    unsigned short* __restrict__ kbh, unsigned short* __restrict__ kbhT) {
    __shared__ unsigned short tl[64][72];
    const int t = threadIdx.x;
    const int n0 = blockIdx.x * 64;
    const int h = blockIdx.y;
    const float mx = key2f(gmax[h]);
    const float4* s4 = (const float4*)kb;
    #pragma unroll
    for (int it = 0; it < 4; ++it) {
        int idx = t + it * 256;       // 1024 = 64 n x 16 c4
        int n = idx >> 4, c4 = idx & 15;
        ushort4 u = make_ushort4(0, 0, 0, 0);
        if (n0 + n < NN) {
            float4 v = s4[(size_t)(n0 + n) * 64 + h * 16 + c4];
            u.x = f2bf(0.125f * (__expf(v.x - mx) + 1e-6f));
            u.y = f2bf(0.125f * (__expf(v.y - mx) + 1e-6f));
            u.z = f2bf(0.125f * (__expf(v.z - mx) + 1e-6f));
            u.w = f2bf(0.125f * (__expf(v.w - mx) + 1e-6f));
            *(ushort4*)&kbh[(size_t)(n0 + n) * NHD + h * DD + c4 * 4] = u;
        }
        tl[c4 * 4 + 0][n] = u.x;
        tl[c4 * 4 + 1][n] = u.y;
        tl[c4 * 4 + 2][n] = u.z;
        tl[c4 * 4 + 3][n] = u.w;
    }
    __syncthreads();
    uint4* d4 = (uint4*)kbhT;
    #pragma unroll
    for (int it = 0; it < 2; ++it) {
        int idx = t + it * 256;       // 512 = 64 m x 8 g
        int m = idx >> 3, g = idx & 7;
        d4[(size_t)(h * 64 + m) * PITCH4 + (n0 >> 3) + g] = *(uint4*)&tl[m][g * 8];
    }
}

// ---------------------------------------------------------------- K3b: transpose bf16 [n][256] -> bf16 [h*64+c][n]
__global__ __launch_bounds__(256) void transp_bf16_kernel(
    const unsigned short* __restrict__ src, unsigned short* __restrict__ dst) {
    __shared__ unsigned short tl[64][72];
    const int t = threadIdx.x;
    const int nt = blockIdx.x * 64;
    const int h = blockIdx.y;
    const uint4* s4 = (const uint4*)src;
    #pragma unroll
    for (int it = 0; it < 2; ++it) {
        int idx = t + it * 256;       // 512 = 64 n x 8 g
        int n = idx >> 3, g = idx & 7;
        uint4 v = make_uint4(0u, 0u, 0u, 0u);
        if (nt + n < NN) v = s4[(size_t)(nt + n) * 32 + h * 8 + g];
        const unsigned short* e = (const unsigned short*)&v;
        #pragma unroll
        for (int j = 0; j < 8; ++j) tl[g * 8 + j][n] = e[j];
    }
    __syncthreads();
    uint4* d4 = (uint4*)dst;
    #pragma unroll
    for (int it = 0; it < 2; ++it) {
        int idx = t + it * 256;
        int m = idx >> 3, g = idx & 7;
        d4[(size_t)(h * 64 + m) * PITCH4 + (nt >> 3) + g] = *(uint4*)&tl[m][g * 8];
    }
}

// ---------------------------------------------------------------- K4: kvs via MFMA bf16
__global__ __launch_bounds__(512) void kvs_kernel(
    const unsigned short* __restrict__ kbhT, const unsigned short* __restrict__ vbhT,
    const float* __restrict__ gum,
    unsigned short* __restrict__ kvsp, float* __restrict__ ksp, float* __restrict__ ksump) {
    __shared__ __align__(16) unsigned short kpa[64 * 64];
    __shared__ __align__(16) unsigned short va [64 * 64];
    __shared__ __align__(16) unsigned short kpwa[64 * 64];
    __shared__ float w_sh[KK][256];
    const int c = blockIdx.x, h = blockIdx.y;
    const int t = threadIdx.x;
    const int n0 = c * CHUNK;
    const int n1 = n0 + CHUNK;
    for (int i = t; i < 256; i += 512) {
        int n = n0 + i;
        bool ok = (i < CHUNK);
        #pragma unroll
        for (int k = 0; k < KK; ++k)
            w_sh[k][i] = ok ? __expf(gum[n * 24 + h * KK + k] * 4.0f) : 0.f;
    }
    const int m_ = t >> 3, g_ = t & 7;
    const int w = t >> 6, lane = t & 63, lrow = lane & 15, lk = lane >> 4;
    const int ds = w & 3, mh = w >> 2;
    const int arow = ds * 16 + lrow;
    f32x4 acc[KK][2];
    #pragma unroll
    for (int k = 0; k < KK; ++k) {
        acc[k][0] = (f32x4){0.f, 0.f, 0.f, 0.f};
        acc[k][1] = (f32x4){0.f, 0.f, 0.f, 0.f};
    }
    float ks_acc[KK] = {0.f, 0.f, 0.f, 0.f, 0.f, 0.f};
    float ksum_acc = 0.f;
    const uint4* kT4 = (const uint4*)kbhT;
    const uint4* vT4 = (const uint4*)vbhT;
    #pragma unroll
    for (int s = 0; s < 4; ++s) {
        const int nb = n0 + s * 64;
        __syncthreads();
        uint4 kvv = kT4[(size_t)(h * 64 + m_) * PITCH4 + (nb >> 3) + g_];
        uint4 vvv = vT4[(size_t)(h * 64 + m_) * PITCH4 + (nb >> 3) + g_];
        const int slot = g_ ^ (m_ & 7);
        *(uint4*)&kpa[m_ * 64 + slot * 8] = kvv;
        *(uint4*)&va [m_ * 64 + slot * 8] = vvv;
        float kf[8];
        {
            const unsigned short* ke = (const unsigned short*)&kvv;
            float sl = 0.f;
            int nbase = nb + g_ * 8;
            #pragma unroll
            for (int e = 0; e < 8; ++e) {
                kf[e] = bf2f(ke[e]);
                if (nbase + e < n1) sl += kf[e];
            }
            sl += __shfl_xor(sl, 1, 64);
            sl += __shfl_xor(sl, 2, 64);
            sl += __shfl_xor(sl, 4, 64);
            if (g_ == 0) ksum_acc += sl;
        }
        __syncthreads();
        bf16x8 a0 = *(const bf16x8*)&va[arow * 64 + ((lk ^ (arow & 7)) * 8)];
        bf16x8 a1 = *(const bf16x8*)&va[arow * 64 + (((lk + 4) ^ (arow & 7)) * 8)];
        const int bw = s * 64;
        const int gg = g_ ^ (m_ & 7);
        #pragma unroll
        for (int k = 0; k < KK; ++k) {
            {
                unsigned short ov[8];
                float sl = 0.f;
                #pragma unroll
                for (int e = 0; e < 8; ++e) {
                    float p = kf[e] * w_sh[k][bw + gg * 8 + e];
                    sl += p;
                    ov[e] = f2bf(p);
                }
                *(uint4*)&kpwa[m_ * 64 + g_ * 8] = *(uint4*)ov;
                sl += __shfl_xor(sl, 1, 64);
                sl += __shfl_xor(sl, 2, 64);
                sl += __shfl_xor(sl, 4, 64);
                if (g_ == 0) ks_acc[k] += sl;
            }
            __syncthreads();
            #pragma unroll
            for (int mt = 0; mt < 2; ++mt) {
                int m = (mh * 2 + mt) * 16 + lrow;
                bf16x8 b0 = *(const bf16x8*)&kpwa[m * 64 + ((lk ^ (m & 7)) * 8)];
                bf16x8 b1 = *(const bf16x8*)&kpwa[m * 64 + (((lk + 4) ^ (m & 7)) * 8)];
                acc[k][mt] = __builtin_amdgcn_mfma_f32_16x16x32_bf16(a0, b0, acc[k][mt], 0, 0, 0);
                acc[k][mt] = __builtin_amdgcn_mfma_f32_16x16x32_bf16(a1, b1, acc[k][mt], 0, 0, 0);
            }
            __syncthreads();
        }
    }
    const size_t cb = (size_t)(c * HH + h) * KK;
    #pragma unroll
    for (int k = 0; k < KK; ++k)
        #pragma unroll
        for (int mt = 0; mt < 2; ++mt) {
            int m = (mh * 2 + mt) * 16 + lrow;
            #pragma unroll
            for (int r = 0; r < 4; ++r) {
                int d = ds * 16 + lk * 4 + r;
                kvsp[(cb + k) * 4096 + d * 64 + m] = f2bf(acc[k][mt][r]);
            }
        }
    if (g_ == 0) {
        #pragma unroll
        for (int k = 0; k < KK; ++k)
            ksp[(cb + k) * 64 + m_] = ks_acc[k];
        ksump[(size_t)(c * HH + h) * 64 + m_] = ksum_acc;
    }
}

// ---------------------------------------------------------------- K5: reduce bf16 partials -> kvshT, f32 ks/ksum
__global__ void reduce_kernel(const unsigned short* __restrict__ kvsp,
                              const float* __restrict__ ksp, const float* __restrict__ ksump,
                              unsigned short* __restrict__ kvshT, float* __restrict__ kss,
                              float* __restrict__ ksum) {
    int idx = blockIdx.x * 256 + threadIdx.x;
    if (idx < 98304) {
        float s = 0.f;
        for (int c = 0; c < NCS; ++c) s += bf2f(kvsp[c * 98304 + idx]);
        kvshT[idx] = f2bf(s);
    } else if (idx < 98304 + 1536) {
        int o = idx - 98304;
        float s = 0.f;
        for (int c = 0; c < NCS; ++c) s += ksp[c * 1536 + o];
        kss[o] = s;
    } else if (idx < 98304 + 1536 + 256) {
        int o = idx - 98304 - 1536;
        float s = 0.f;
        for (int c = 0; c < NCS; ++c) s += ksump[c * 256 + o];
        ksum[o] = s;
    }
}

// ---------------------------------------------------------------- K6: znum via MFMA bf16 (proven)
__global__ __launch_bounds__(256) void znum_kernel(
    const unsigned short* __restrict__ qbh, const unsigned short* __restrict__ kvshT,
    const float* __restrict__ kss, const float* __restrict__ ksum,
    float* __restrict__ zout, float* __restrict__ nrm) {
    __shared__ __align__(16) unsigned short qpa[64 * 64];
    __shared__ __align__(16) unsigned short bt[6 * 64 * 64];
    __shared__ float ks_sh[384];
    __shared__ float ksum_sh[64];
    __shared__ float zdi[64 * 6];
    const int t = threadIdx.x;
    const int h = blockIdx.y;
    const int n0 = blockIdx.x * 64;
    const uint4* qg = (const uint4*)qbh;
    #pragma unroll
    for (int q = 0; q < 2; ++q) {
        int idx = t + q * 256;
        int row = idx >> 3, c8 = idx & 7;
        int n = n0 + row;
        uint4 v = make_uint4(0u, 0u, 0u, 0u);
        if (n < NN) v = qg[n * 32 + h * 8 + c8];
        *(uint4*)&qpa[row * 64 + ((c8 ^ (row & 7)) * 8)] = v;
    }
    const uint4* bg = (const uint4*)kvshT;
    #pragma unroll
    for (int q = 0; q < 12; ++q) {
        int idx = t + q * 256;
        int kd = idx >> 3, c8 = idx & 7;
        *(uint4*)&bt[kd * 64 + ((c8 ^ (kd & 7)) * 8)] = bg[h * 3072 + idx];
    }
    for (int i = t; i < 384; i += 256) ks_sh[i] = kss[h * 384 + i];
    if (t < 64) ksum_sh[t] = ksum[h * 64 + t];
    __syncthreads();
    for (int idx = t; idx < 512; idx += 256) {
        if (idx < 384) {
            int node = idx / 6, k = idx - node * 6;
            int swz = (node & 7) << 3;
            float s = 0.f;
            for (int m = 0; m < 64; ++m)
                s += bf2f(qpa[node * 64 + (m ^ swz)]) * ks_sh[k * 64 + m];
            zdi[node * 6 + k] = 1.0f / s;
        } else if (idx < 448) {
            int node = idx - 384;
            int swz = (node & 7) << 3;
            float s = 0.f;
            for (int m = 0; m < 64; ++m)
                s += bf2f(qpa[node * 64 + (m ^ swz)]) * ksum_sh[m];
            int n = n0 + node;
            if (n < NN) nrm[n * HH + h] = s;
        }
    }
    __syncthreads();
    const int w = t >> 6, lane = t & 63;
    const int lrow = lane & 15, lk = lane >> 4;
    const int arow = w * 16 + lrow;
    const int aswz = (arow & 7) << 3;
    bf16x8 a0 = *(const bf16x8*)&qpa[arow * 64 + ((lk * 8) ^ aswz)];
    bf16x8 a1 = *(const bf16x8*)&qpa[arow * 64 + ((lk * 8 + 32) ^ aswz)];
    const float inv6 = 1.0f / 6.0f;
    #pragma unroll
    for (int dt = 0; dt < 4; ++dt) {
        f32x4 outv = {0.f, 0.f, 0.f, 0.f};
        #pragma unroll
        for (int k = 0; k < KK; ++k) {
            int kd = k * 64 + dt * 16 + lrow;
            int sw = (kd & 7) << 3;
            bf16x8 b0 = *(const bf16x8*)&bt[kd * 64 + ((lk * 8) ^ sw)];
            bf16x8 b1 = *(const bf16x8*)&bt[kd * 64 + ((lk * 8 + 32) ^ sw)];
            f32x4 acc = {0.f, 0.f, 0.f, 0.f};
            acc = __builtin_amdgcn_mfma_f32_16x16x32_bf16(a0, b0, acc, 0, 0, 0);
            acc = __builtin_amdgcn_mfma_f32_16x16x32_bf16(a1, b1, acc, 0, 0, 0);
            #pragma unroll
            for (int r = 0; r < 4; ++r)
                outv[r] += zdi[(w * 16 + lk * 4 + r) * 6 + k] * acc[r];
        }
        #pragma unroll
        for (int r = 0; r < 4; ++r) {
            int n = n0 + w * 16 + lk * 4 + r;
            if (n < NN) zout[(size_t)n * NHD + h * DD + dt * 16 + lrow] = outv[r] * inv6;
        }
    }
}

// ---------------------------------------------------------------- K7: output projection (f32 out)
__global__ __launch_bounds__(256) void outproj_kernel(
    const float* __restrict__ zout, const float* __restrict__ Wo,
    const float* __restrict__ bo, float* __restrict__ out) {
    __shared__ float zsh[16][NHD];
    const int t = threadIdx.x;
    const int n0 = blockIdx.x * 16;
    #pragma unroll
    for (int q = 0; q < 16; ++q) {
        int idx = t + q * 256;
        int nn2 = idx >> 8, r = idx & 255;
        zsh[nn2][r] = zout[(n0 + nn2) * NHD + r];
    }
    __syncthreads();
    const int c = t & 63, g = t >> 6;
    float acc[4];
    #pragma unroll
    for (int i = 0; i < 4; ++i) acc[i] = bo[c];
    for (int r = 0; r < 256; ++r) {
        float w = Wo[r * 64 + c];
        #pragma unroll
        for (int i = 0; i < 4; ++i) acc[i] += zsh[g + 4 * i][r] * w;
    }
    #pragma unroll
    for (int i = 0; i < 4; ++i)
        out[(n0 + g + 4 * i) * 64 + c] = acc[i];
}

// ---------------------------------------------------------------- K8: edges, bf16 gather
__global__ __launch_bounds__(256) void edge_bf16_kernel(
    const unsigned short* __restrict__ qbh, const unsigned short* __restrict__ kbh,
    const int* __restrict__ ei, const float* __restrict__ nrm,
    float* __restrict__ out) {
    const int t = threadIdx.x;
    const int lane5 = t & 31;
    const int e = blockIdx.x * 8 + (t >> 5);
    const int s = ei[e], d = ei[EE + e];
    const uint4* q4 = (const uint4*)qbh;
    const uint4* k4 = (const uint4*)kbh;
    uint4 qv = q4[d * 32 + lane5];
    uint4 kv = k4[s * 32 + lane5];
    const unsigned short* qs = (const unsigned short*)&qv;
    const unsigned short* ks = (const unsigned short*)&kv;
    float p = 0.f;
    #pragma unroll
    for (int i = 0; i < 8; ++i) p += bf2f(qs[i]) * bf2f(ks[i]);
    p += __shfl_xor(p, 1, 64);
    p += __shfl_xor(p, 2, 64);
    p += __shfl_xor(p, 4, 64);
    if ((lane5 & 7) == 0) {
        int h = lane5 >> 3;
        out[ZOFF + e * 4 + h] = p / nrm[d * HH + h];
    }
}

// ---------------------------------------------------------------- launch
extern "C" void kernel_launch(void* const* d_in, const int* in_sizes, int n_in,
                              void* d_out, int out_size, void* d_ws, size_t ws_size,
                              hipStream_t stream) {
    (void)in_sizes; (void)n_in; (void)out_size;
    const float* z  = (const float*)d_in[0];
    const float* Wq = (const float*)d_in[1];
    const float* bq = (const float*)d_in[2];
    const float* Wk = (const float*)d_in[3];
    const float* bk = (const float*)d_in[4];
    const float* Wv = (const float*)d_in[5];
    const float* bv = (const float*)d_in[6];
    const float* Wo = (const float*)d_in[7];
    const float* bo = (const float*)d_in[8];
    const float* proj = (const float*)d_in[9];
    const float* gum  = (const float*)d_in[10];
    const int*   ei   = (const int*)d_in[11];
    float* out = (float*)d_out;
    float* ws = (float*)d_ws;

    if (ws_size / 4 < (size_t)38673348) return;

    // region map (floats):
    // [0, 7.68M)        : zh + WT (pre-qkv) -> kvs partials (post-feat)
    // [7.68M, 15.36M)   : kb f32 (dd - diag)
    // [15.36M, 23.04M)  : vh bf16 (first 3.84M) -> zout f32
    // [23.04M, ...)     : kvshT, kss, ksum, nrm, gmax
    // [23.26M, 27.1M)   : qbh (q-raw bf16 -> qp bf16)
    // [27.1M, 30.94M)   : kbh (k-raw bf16 -> kp bf16)
    // [30.94M, 38.67M)  : kbhT, vbhT
    float* kb    = ws + 7680000;
    float* zout  = ws + 15360000;
    unsigned short* vh = (unsigned short*)(ws + 15360000);
    unsigned short* kvshT = (unsigned short*)(ws + 23040000);
    float* kss   = ws + 23138304;
    float* ksum  = ws + 23139840;
    float* nrm   = ws + 23140096;
    unsigned* gmax = (unsigned*)(ws + 23260096);
    unsigned short* qbh = (unsigned short*)(ws + 23260100);
    unsigned short* kbh = (unsigned short*)(ws + 27100100);
    unsigned short* kbhT = (unsigned short*)(ws + 30940100);
    unsigned short* vbhT = (unsigned short*)(ws + 34806724);
    unsigned short* zh = (unsigned short*)ws;                 // dead after qkv
    unsigned short* WT = (unsigned short*)(ws + 3840000);     // dead after qkv
    float* ksp   = ws;                                        // post-feat aliases
    float* ksump = ws + 192000;
    unsigned short* kvsp = (unsigned short*)(ws + 224000);

    init_kernel<<<1, 64, 0, stream>>>(gmax);
    zcast_kernel<<<3750, 256, 0, stream>>>(z, zh);
    wtransp_kernel<<<dim3(8, 3), 256, 0, stream>>>(Wq, Wk, Wv, WT);
    qkv_mfma_kernel<<<dim3(235, 3), 256, 0, stream>>>(zh, WT, bq, bk, bv, qbh, kbh, vh);
    transp_bf16_kernel<<<dim3(472, HH), 256, 0, stream>>>(vh, vbhT);
    feat_kernel<<<dim3(469, HH), 256, 0, stream>>>(qbh, kbh, kb, proj, gmax, qbh);
    kfin_tr_kernel<<<dim3(472, HH), 256, 0, stream>>>(kb, gmax, kbh, kbhT);
    kvs_kernel<<<dim3(NCS, HH), 512, 0, stream>>>(kbhT, vbhT, gum, kvsp, ksp, ksump);
    reduce_kernel<<<392, 256, 0, stream>>>(kvsp, ksp, ksump, kvshT, kss, ksum);
    znum_kernel<<<dim3(469, HH), 256, 0, stream>>>(qbh, kvshT, kss, ksum, zout, nrm);
    outproj_kernel<<<1875, 256, 0, stream>>>(zout, Wo, bo, out);
    edge_bf16_kernel<<<60000, 256, 0, stream>>>(qbh, kbh, ei, nrm, out);
}